// Round 7
// baseline (1160.864 us; speedup 1.0000x reference)
//
#include <hip/hip_runtime.h>
#include <hip/hip_bf16.h>

#define F 64
#define GRAPHS 512
#define CLASSES 10
#define SCAN_T 1024
#define OUTCAP 8448   // bucket CSR slots (mean ~4350, sigma ~64 — never overflows)

// ---------------- deg (real edges only) + graph bounds fused ----------------
__global__ void deg_gb_kernel(const int* __restrict__ ei, int E, int* __restrict__ deg,
                              const int* __restrict__ batch, int N, int* __restrict__ gstart,
                              int DB) {
    int b = blockIdx.x;
    if (b < DB) {
        int i = b * 256 + threadIdx.x;
        if (i < E) atomicAdd(&deg[ei[E + i]], 1);
    } else {
        int g = (b - DB) * 256 + threadIdx.x;
        if (g > GRAPHS) return;
        int lo = 0, hi = N;
        while (lo < hi) {
            int mid = (lo + hi) >> 1;
            if (batch[mid] < g) lo = mid + 1; else hi = mid;
        }
        gstart[g] = lo;
    }
}

// ---------------- scan (degree = deg[i] + 1 for the self loop) ----------------
__global__ void scan_partial(const int* __restrict__ deg, int N, int* __restrict__ partial) {
    int t = blockIdx.x * blockDim.x + threadIdx.x;
    int chunk = (N + SCAN_T - 1) / SCAN_T;
    int b = t * chunk;
    int e = min(N, b + chunk);
    int s = 0;
    for (int i = b; i < e; ++i) s += deg[i] + 1;
    partial[t] = s;
}

__global__ void scan_block(int* __restrict__ partial) {   // 1 block, 1024 threads
    __shared__ int wsum[16];
    int t = threadIdx.x;
    int lane = t & 63, w = t >> 6;
    int orig = partial[t];
    int v = orig;
    #pragma unroll
    for (int o = 1; o < 64; o <<= 1) {
        int u = __shfl_up(v, o);
        if (lane >= o) v += u;
    }
    if (lane == 63) wsum[w] = v;
    __syncthreads();
    if (t == 0) {
        int run = 0;
        for (int i = 0; i < 16; ++i) { int x = wsum[i]; wsum[i] = run; run += x; }
    }
    __syncthreads();
    v += wsum[w];
    partial[t] = v - orig;   // exclusive prefix
}

// writes rowptr, fill (=segment start, overflow-fallback only), and per-bucket
// staging base bfill[b] = rowptr[b*256] - b*256 (real-edge cumulative offset)
__global__ void scan_final(const int* __restrict__ deg, const int* __restrict__ partial,
                           int N, int* __restrict__ rowptr, int* __restrict__ fill,
                           int* __restrict__ bfill) {
    int t = blockIdx.x * blockDim.x + threadIdx.x;
    int chunk = (N + SCAN_T - 1) / SCAN_T;
    int b = t * chunk;
    int e = min(N, b + chunk);
    int run = partial[t];
    for (int i = b; i < e; ++i) {
        rowptr[i] = run;
        fill[i] = run;
        if ((i & 255) == 0) bfill[i >> 8] = run - i;
        run += deg[i] + 1;
    }
    if (t == SCAN_T - 1) rowptr[N] = run;
}

// ---------------- pass A: bucketed edge append ----------------
// Appends advance 391 dense tails; a 64B line's ~16 entries are allocated within
// microseconds, so HBM write-combining can merge them (vs. fully-random scatter
// where each 4B store cost a full 64B line RMW — measured 104MB for 6.4MB).
__global__ void bucket_scatter(const int* __restrict__ ei, int E,
                               int* __restrict__ bfill, unsigned* __restrict__ stage) {
    int i = blockIdx.x * blockDim.x + threadIdx.x;
    if (i >= E) return;
    int s = ei[i], d = ei[E + i];
    int pos = atomicAdd(&bfill[d >> 8], 1);
    stage[pos] = (unsigned)s | ((unsigned)(d & 255) << 24);   // N < 2^24
}

// ---------------- pass B: place bucket into CSR via LDS, coalesced flush ----------------
__global__ void bucket_place(const unsigned* __restrict__ stage, const int* __restrict__ rowptr,
                             int* __restrict__ fill, int* __restrict__ csr_src, int N) {
    __shared__ int rp[257];
    __shared__ int cnt[256];
    __shared__ int out[OUTCAP];
    int tid = threadIdx.x;
    int n0 = blockIdx.x << 8;
    int nn = min(256, N - n0);
    for (int j = tid; j <= nn; j += 256) rp[j] = rowptr[n0 + j];
    cnt[tid] = 0;
    __syncthreads();
    int cb = rp[0];
    int csrlen = rp[nn] - cb;
    int estart = cb - n0;
    int eend = rp[nn] - (n0 + nn);
    if (csrlen <= OUTCAP) {
        for (int i = estart + tid; i < eend; i += 256) {
            unsigned w = stage[i];
            int dl = w >> 24;
            int p = rp[dl] - cb + atomicAdd(&cnt[dl], 1);
            out[p] = (int)(w & 0xFFFFFFu);
        }
        __syncthreads();
        for (int j = tid; j < nn; j += 256) out[rp[j + 1] - 1 - cb] = n0 + j;  // self loops
        __syncthreads();
        for (int i = tid; i < csrlen; i += 256) csr_src[cb + i] = out[i];      // coalesced
    } else {
        // overflow fallback (statistically unreachable)
        for (int i = estart + tid; i < eend; i += 256) {
            unsigned w = stage[i];
            int d = n0 + (int)(w >> 24);
            int p = atomicAdd(&fill[d], 1);
            csr_src[p] = (int)(w & 0xFFFFFFu);
        }
        for (int j = tid; j < nn; j += 256) csr_src[rp[j + 1] - 1] = n0 + j;
    }
}

// ---------------- GEMM + fused score epilogue; h packed bf16 via LDS flush ----------------
template<int K>
__device__ __forceinline__ void gemm_body(float* smem,
                                          const float* __restrict__ x, const float* __restrict__ W,
                                          const float* __restrict__ asrc, const float* __restrict__ adst,
                                          unsigned* __restrict__ hb, float* __restrict__ es,
                                          float* __restrict__ ed, int N, int bid) {
    constexpr int ROWS = 16;
    constexpr int KP = K + 4;
    constexpr int K4 = K / 4;
    float* Ws = smem;                                  // [64][KP] transposed
    float* xs = smem + 64 * KP;                        // [ROWS][K]
    unsigned* hs = (unsigned*)(smem + 64 * KP + ROWS * K);  // [ROWS*32] packed bf16x2
    int base = bid * ROWS;

    {
        int c = threadIdx.x & 63;
        int q0 = threadIdx.x >> 6;
        #pragma unroll
        for (int it = 0; it < K4 / 4; ++it) {
            int q = q0 + 4 * it;
            float4 v;
            v.x = W[(4 * q + 0) * F + c];
            v.y = W[(4 * q + 1) * F + c];
            v.z = W[(4 * q + 2) * F + c];
            v.w = W[(4 * q + 3) * F + c];
            *(float4*)&Ws[c * KP + 4 * q] = v;
        }
    }
    int nrows = min(ROWS, N - base);
    float4* xs4 = (float4*)xs;
    const float4* x4 = (const float4*)x;
    for (int i = threadIdx.x; i < nrows * K4; i += 256) {
        int r = i / K4, k4 = i - r * K4;
        xs4[r * K4 + k4] = x4[(size_t)(base + r) * K4 + k4];
    }
    __syncthreads();

    int wave = threadIdx.x >> 6, lane = threadIdx.x & 63;
    float as_l = asrc[lane];
    float ad_l = adst[lane];
    const float4* wr = (const float4*)&Ws[lane * KP];
    const float4* xr0 = (const float4*)&xs[(wave + 0) * K];
    const float4* xr1 = (const float4*)&xs[(wave + 4) * K];
    const float4* xr2 = (const float4*)&xs[(wave + 8) * K];
    const float4* xr3 = (const float4*)&xs[(wave + 12) * K];
    float a0 = 0.f, a1 = 0.f, a2 = 0.f, a3 = 0.f;
    #pragma unroll 8
    for (int k4 = 0; k4 < K4; ++k4) {
        float4 wv = wr[k4];
        float4 v0 = xr0[k4], v1 = xr1[k4], v2 = xr2[k4], v3 = xr3[k4];
        a0 = fmaf(v0.x, wv.x, fmaf(v0.y, wv.y, fmaf(v0.z, wv.z, fmaf(v0.w, wv.w, a0))));
        a1 = fmaf(v1.x, wv.x, fmaf(v1.y, wv.y, fmaf(v1.z, wv.z, fmaf(v1.w, wv.w, a1))));
        a2 = fmaf(v2.x, wv.x, fmaf(v2.y, wv.y, fmaf(v2.z, wv.z, fmaf(v2.w, wv.w, a2))));
        a3 = fmaf(v3.x, wv.x, fmaf(v3.y, wv.y, fmaf(v3.z, wv.z, fmaf(v3.w, wv.w, a3))));
    }
    float accs[4] = {a0, a1, a2, a3};
    #pragma unroll
    for (int rr = 0; rr < 4; ++rr) {
        int r = wave + 4 * rr;
        float acc = accs[rr];
        unsigned ub = __float_as_uint(acc);
        unsigned rb = (ub + 0x7FFF + ((ub >> 16) & 1)) >> 16;   // RNE bf16 bits
        unsigned pb = (unsigned)__shfl_xor((int)rb, 1);
        if ((lane & 1) == 0) hs[r * 32 + (lane >> 1)] = (pb << 16) | rb;
        float vs = acc * as_l;
        float vd = acc * ad_l;
        #pragma unroll
        for (int o = 32; o > 0; o >>= 1) {
            vs += __shfl_down(vs, o);
            vd += __shfl_down(vd, o);
        }
        if (lane == 0 && r < nrows) { es[base + r] = vs; ed[base + r] = vd; }
    }
    __syncthreads();
    unsigned* hbase = hb + (size_t)base * 32;
    for (int i = threadIdx.x; i < nrows * 32; i += 256) hbase[i] = hs[i];
}

template<int K>
__global__ void gemm_kernel(const float* __restrict__ x, const float* __restrict__ W,
                            const float* __restrict__ asrc, const float* __restrict__ adst,
                            unsigned* __restrict__ hb, float* __restrict__ es,
                            float* __restrict__ ed, int N) {
    extern __shared__ float smem[];
    gemm_body<K>(smem, x, W, asrc, adst, hb, es, ed, N, blockIdx.x);
}

// ---------------- per-node segment softmax + aggregation (bf16 h gather) ----------------
__device__ __forceinline__ float unpack_h(unsigned pw, int lane) {
    return __uint_as_float((lane & 1) ? (pw & 0xFFFF0000u) : (pw << 16));
}

__global__ void gat_aggregate(const unsigned* __restrict__ hb, const float* __restrict__ es,
                              const float* __restrict__ ed, const int* __restrict__ rowptr,
                              const int* __restrict__ csr_src, const float* __restrict__ bias,
                              float* __restrict__ xout, int N) {
    __shared__ float2 sw[4][64];
    int wave = threadIdx.x >> 6, lane = threadIdx.x & 63;
    int node = blockIdx.x * 4 + wave;
    if (node >= N) return;
    int beg = rowptr[node], end = rowptr[node + 1];
    int cnt = end - beg;
    float edn = ed[node];
    int half = lane >> 1;
    float acc;

    if (cnt <= 64) {
        int s = 0;
        float e = -1e30f;
        if (lane < cnt) {
            s = csr_src[beg + lane];
            float t = es[s] + edn;
            e = t > 0.f ? t : 0.2f * t;
        }
        float m = e;
        #pragma unroll
        for (int o = 32; o > 0; o >>= 1) m = fmaxf(m, __shfl_xor(m, o));
        float w = (lane < cnt) ? __expf(e - m) : 0.f;
        float den = w;
        #pragma unroll
        for (int o = 32; o > 0; o >>= 1) den += __shfl_xor(den, o);
        sw[wave][lane] = make_float2(__int_as_float(s), w);
        float a0 = 0.f, a1 = 0.f, a2 = 0.f, a3 = 0.f;
        int i = 0;
        for (; i + 3 < cnt; i += 4) {
            float2 p0 = sw[wave][i];
            float2 p1 = sw[wave][i + 1];
            float2 p2 = sw[wave][i + 2];
            float2 p3 = sw[wave][i + 3];
            float h0 = unpack_h(hb[(size_t)__float_as_int(p0.x) * 32 + half], lane);
            float h1 = unpack_h(hb[(size_t)__float_as_int(p1.x) * 32 + half], lane);
            float h2 = unpack_h(hb[(size_t)__float_as_int(p2.x) * 32 + half], lane);
            float h3 = unpack_h(hb[(size_t)__float_as_int(p3.x) * 32 + half], lane);
            a0 = fmaf(p0.y, h0, a0);
            a1 = fmaf(p1.y, h1, a1);
            a2 = fmaf(p2.y, h2, a2);
            a3 = fmaf(p3.y, h3, a3);
        }
        for (; i < cnt; ++i) {
            float2 p = sw[wave][i];
            a0 = fmaf(p.y, unpack_h(hb[(size_t)__float_as_int(p.x) * 32 + half], lane), a0);
        }
        acc = ((a0 + a1) + (a2 + a3)) / (den + 1e-16f);
    } else {
        float m = -1e30f;
        for (int j = beg + lane; j < end; j += 64) {
            float e = es[csr_src[j]] + edn;
            e = e > 0.f ? e : 0.2f * e;
            m = fmaxf(m, e);
        }
        #pragma unroll
        for (int o = 32; o > 0; o >>= 1) m = fmaxf(m, __shfl_xor(m, o));
        float a = 0.f, den = 0.f;
        for (int j = beg; j < end; ++j) {
            int s = csr_src[j];
            float e = es[s] + edn;
            e = e > 0.f ? e : 0.2f * e;
            float w = __expf(e - m);
            den += w;
            a = fmaf(w, unpack_h(hb[(size_t)s * 32 + half], lane), a);
        }
        acc = a / (den + 1e-16f);
    }
    float v = acc + bias[lane];
    v = v > 0.f ? v : 0.f;   // relu
    xout[(size_t)node * F + lane] = v;
}

// ---------------- mean pooling: 4 blocks per graph, register accumulate ----------------
__global__ void pool_kernel(const float* __restrict__ x1, const float* __restrict__ x2,
                            const float* __restrict__ x3, const int* __restrict__ gstart,
                            float* __restrict__ pooled) {
    int g = blockIdx.x >> 2;
    int seg = blockIdx.x & 3;
    int f = threadIdx.x;               // 0..191
    int lane = f & 63;
    const float* src = (f < 64) ? x1 : (f < 128) ? x2 : x3;
    int lo = gstart[g], hi = gstart[g + 1];
    int len = hi - lo;
    int chunk = (len + 3) >> 2;
    int b = lo + seg * chunk;
    int e = min(hi, b + chunk);
    float s0 = 0.f, s1 = 0.f, s2 = 0.f, s3 = 0.f;
    int i = b;
    for (; i + 3 < e; i += 4) {
        s0 += src[(size_t)i * F + lane];
        s1 += src[(size_t)(i + 1) * F + lane];
        s2 += src[(size_t)(i + 2) * F + lane];
        s3 += src[(size_t)(i + 3) * F + lane];
    }
    for (; i < e; ++i) s0 += src[(size_t)i * F + lane];
    float s = (s0 + s1) + (s2 + s3);
    atomicAdd(&pooled[g * 192 + f], s);
}

// ---------------- final linear + softmax ----------------
__global__ void head_kernel(const float* __restrict__ pooled, const int* __restrict__ gstart,
                            const float* __restrict__ Wo, const float* __restrict__ bo,
                            float* __restrict__ out) {
    int g = blockIdx.x * blockDim.x + threadIdx.x;
    if (g >= GRAPHS) return;
    int cntg = gstart[g + 1] - gstart[g];
    float inv = 1.0f / fmaxf((float)cntg, 1.0f);
    float acc[CLASSES];
    #pragma unroll
    for (int c = 0; c < CLASSES; ++c) acc[c] = bo[c];
    for (int f = 0; f < 192; ++f) {
        float p = pooled[g * 192 + f] * inv;
        #pragma unroll
        for (int c = 0; c < CLASSES; ++c) acc[c] = fmaf(p, Wo[f * CLASSES + c], acc[c]);
    }
    float mx = acc[0];
    #pragma unroll
    for (int c = 1; c < CLASSES; ++c) mx = fmaxf(mx, acc[c]);
    float s = 0.f;
    #pragma unroll
    for (int c = 0; c < CLASSES; ++c) { acc[c] = __expf(acc[c] - mx); s += acc[c]; }
    float invs = 1.0f / s;
    #pragma unroll
    for (int c = 0; c < CLASSES; ++c) out[g * CLASSES + c] = acc[c] * invs;
}

extern "C" void kernel_launch(void* const* d_in, const int* in_sizes, int n_in,
                              void* d_out, int out_size, void* d_ws, size_t ws_size,
                              hipStream_t stream) {
    const float* x   = (const float*)d_in[0];
    const int* ei    = (const int*)d_in[1];
    const int* batch = (const int*)d_in[2];
    const float* W1  = (const float*)d_in[3];
    const float* a1s = (const float*)d_in[4];
    const float* a1d = (const float*)d_in[5];
    const float* b1  = (const float*)d_in[6];
    const float* W2  = (const float*)d_in[7];
    const float* a2s = (const float*)d_in[8];
    const float* a2d = (const float*)d_in[9];
    const float* b2  = (const float*)d_in[10];
    const float* W3  = (const float*)d_in[11];
    const float* a3s = (const float*)d_in[12];
    const float* a3d = (const float*)d_in[13];
    const float* b3  = (const float*)d_in[14];
    const float* Wo  = (const float*)d_in[15];
    const float* bo  = (const float*)d_in[16];
    float* out = (float*)d_out;

    const int N = in_sizes[2];          // #nodes
    const int E = in_sizes[1] / 2;      // real edges
    const int TOT = E + N;              // with self loops
    const int NB = (N + 255) >> 8;      // buckets

    char* p = (char*)d_ws;
    auto alloc = [&](size_t bytes) { char* r = p; p += (bytes + 255) & ~(size_t)255; return r; };
    float* x1      = (float*)alloc((size_t)N * F * 4);
    float* x2      = (float*)alloc((size_t)N * F * 4);
    float* x3      = (float*)alloc((size_t)N * F * 4);
    unsigned* hb   = (unsigned*)alloc((size_t)N * 32 * 4);   // bf16x2 packed h
    float* es      = (float*)alloc((size_t)N * 4);
    float* ed      = (float*)alloc((size_t)N * 4);
    int* deg       = (int*)alloc((size_t)N * 4);
    int* rowptr    = (int*)alloc((size_t)(N + 1) * 4);
    int* fill      = (int*)alloc((size_t)N * 4);
    int* csr_src   = (int*)alloc((size_t)TOT * 4);
    unsigned* stage= (unsigned*)alloc((size_t)E * 4);
    int* bfill     = (int*)alloc((size_t)NB * 4);
    int* partial   = (int*)alloc((size_t)SCAN_T * 4);
    float* pooled  = (float*)alloc((size_t)GRAPHS * 192 * 4);
    int* gstart    = (int*)alloc((size_t)(GRAPHS + 1) * 4);

    hipMemsetAsync(deg, 0, (size_t)N * 4, stream);
    hipMemsetAsync(pooled, 0, (size_t)GRAPHS * 192 * 4, stream);

    const int DB = (E + 255) / 256;
    const int GB = (N + 15) / 16;
    const size_t SM128 = (size_t)(64 * 132 + 16 * 128) * 4 + 2048;   // W + x + h-stage
    const size_t SM64  = (size_t)(64 * 68 + 16 * 64) * 4 + 2048;
    int node_blocks = (N + 3) / 4;

    // CSR build
    deg_gb_kernel<<<DB + 3, 256, 0, stream>>>(ei, E, deg, batch, N, gstart, DB);
    scan_partial<<<SCAN_T / 256, 256, 0, stream>>>(deg, N, partial);
    scan_block<<<1, SCAN_T, 0, stream>>>(partial);
    scan_final<<<SCAN_T / 256, 256, 0, stream>>>(deg, partial, N, rowptr, fill, bfill);
    bucket_scatter<<<DB, 256, 0, stream>>>(ei, E, bfill, stage);
    bucket_place<<<NB, 256, 0, stream>>>(stage, rowptr, fill, csr_src, N);

    // layer 1
    gemm_kernel<128><<<GB, 256, SM128, stream>>>(x, W1, a1s, a1d, hb, es, ed, N);
    gat_aggregate<<<node_blocks, 256, 0, stream>>>(hb, es, ed, rowptr, csr_src, b1, x1, N);
    // layer 2
    gemm_kernel<64><<<GB, 256, SM64, stream>>>(x1, W2, a2s, a2d, hb, es, ed, N);
    gat_aggregate<<<node_blocks, 256, 0, stream>>>(hb, es, ed, rowptr, csr_src, b2, x2, N);
    // layer 3
    gemm_kernel<64><<<GB, 256, SM64, stream>>>(x2, W3, a3s, a3d, hb, es, ed, N);
    gat_aggregate<<<node_blocks, 256, 0, stream>>>(hb, es, ed, rowptr, csr_src, b3, x3, N);

    // readout
    pool_kernel<<<GRAPHS * 4, 192, 0, stream>>>(x1, x2, x3, gstart, pooled);
    head_kernel<<<(GRAPHS + 255) / 256, 256, 0, stream>>>(pooled, gstart, Wo, bo, out);
}

// Round 8
// 582.001 us; speedup vs baseline: 1.9946x; 1.9946x over previous
//
#include <hip/hip_runtime.h>
#include <hip/hip_bf16.h>

#define F 64
#define GRAPHS 512
#define CLASSES 10
#define SCAN_T 1024
#define NBLK 512       // histogram/scatter blocks (power of 2: logical idx = bucket*NBLK+blk)
#define OUTCAP 8448    // bucket CSR slots (mean ~4350, sigma ~64 — never overflows)

// ---------------- phase 1: per-block LDS histogram over dst buckets (+gbounds) ----------------
__global__ void hist_gb_kernel(const int* __restrict__ ei, int E, int NB,
                               int* __restrict__ hist,
                               const int* __restrict__ batch, int N, int* __restrict__ gstart) {
    int blk = blockIdx.x, tid = threadIdx.x;
    if (blk < NBLK) {
        __shared__ int lh[512];
        lh[tid] = 0; lh[tid + 256] = 0;
        __syncthreads();
        int chunk = (E + NBLK - 1) / NBLK;
        int b = blk * chunk, e = min(E, b + chunk);
        for (int i = b + tid; i < e; i += 256) atomicAdd(&lh[ei[E + i] >> 8], 1);
        __syncthreads();
        for (int j = tid; j < NB; j += 256) hist[blk * NB + j] = lh[j];   // coalesced
    } else {
        int g = (blk - NBLK) * 256 + tid;
        if (g > GRAPHS) return;
        int lo = 0, hi = N;
        while (lo < hi) {
            int mid = (lo + hi) >> 1;
            if (batch[mid] < g) lo = mid + 1; else hi = mid;
        }
        gstart[g] = lo;
    }
}

// ---------------- phase 2: exclusive scan of hist in logical (bucket-major) order --------
// logical l = bucket*NBLK + blk  ->  physical = blk*NB + bucket
__global__ void hscan_partial(const int* __restrict__ hist, int M, int NB,
                              int* __restrict__ partial) {
    int t = blockIdx.x * blockDim.x + threadIdx.x;   // 0..1023
    int chunk = (M + SCAN_T - 1) / SCAN_T;
    int b = t * chunk, e = min(M, b + chunk);
    int s = 0;
    for (int l = b; l < e; ++l) s += hist[(l & (NBLK - 1)) * NB + (l >> 9)];
    partial[t] = s;
}

__global__ void scan_block(int* __restrict__ partial) {   // 1 block, 1024 threads
    __shared__ int wsum[16];
    int t = threadIdx.x;
    int lane = t & 63, w = t >> 6;
    int orig = partial[t];
    int v = orig;
    #pragma unroll
    for (int o = 1; o < 64; o <<= 1) {
        int u = __shfl_up(v, o);
        if (lane >= o) v += u;
    }
    if (lane == 63) wsum[w] = v;
    __syncthreads();
    if (t == 0) {
        int run = 0;
        for (int i = 0; i < 16; ++i) { int x = wsum[i]; wsum[i] = run; run += x; }
    }
    __syncthreads();
    v += wsum[w];
    partial[t] = v - orig;   // exclusive prefix
}

__global__ void hscan_final(const int* __restrict__ hist, const int* __restrict__ partial,
                            int M, int NB, int* __restrict__ shist) {
    int t = blockIdx.x * blockDim.x + threadIdx.x;
    int chunk = (M + SCAN_T - 1) / SCAN_T;
    int b = t * chunk, e = min(M, b + chunk);
    int run = partial[t];
    for (int l = b; l < e; ++l) {
        int ph = (l & (NBLK - 1)) * NB + (l >> 9);
        int v = hist[ph];
        shist[ph] = run;
        run += v;
    }
}

// ---------------- phase 3: binned scatter, LDS cursors only (no global atomics) ----------
__global__ void scatter3(const int* __restrict__ ei, int E, int NB,
                         const int* __restrict__ shist, unsigned* __restrict__ stage) {
    __shared__ int offs[512];
    int blk = blockIdx.x, tid = threadIdx.x;
    for (int j = tid; j < NB; j += 256) offs[j] = shist[blk * NB + j];   // coalesced
    __syncthreads();
    int chunk = (E + NBLK - 1) / NBLK;
    int b = blk * chunk, e = min(E, b + chunk);
    for (int i = b + tid; i < e; i += 256) {
        int s = ei[i], d = ei[E + i];
        int pos = atomicAdd(&offs[d >> 8], 1);                            // LDS atomic
        stage[pos] = (unsigned)s | ((unsigned)(d & 255) << 24);           // N < 2^24
    }
}

// ---------------- phase 4: per-bucket place; derives rowptr; coalesced CSR flush ---------
__global__ void place2(const unsigned* __restrict__ stage, const int* __restrict__ shist,
                       int* __restrict__ rowptr, int* __restrict__ csr_src,
                       int N, int E, int NB) {
    __shared__ int cnt[256];
    __shared__ int cur[256];
    __shared__ int wsum[4];
    __shared__ int out[OUTCAP];
    int tid = threadIdx.x, bkt = blockIdx.x;
    int n0 = bkt << 8;
    int nn = min(256, N - n0);
    int eb = shist[bkt];                                  // logical (bkt,0) == phys bkt
    int ee = (bkt == NB - 1) ? E : shist[bkt + 1];
    int elen = ee - eb;
    int cb = eb + n0;                                     // + one self loop per earlier node
    int csrlen = elen + nn;
    cnt[tid] = 0;
    __syncthreads();
    for (int i = tid; i < elen; i += 256) atomicAdd(&cnt[stage[eb + i] >> 24], 1);
    __syncthreads();
    // 256-wide exclusive scan of per-node segment length (cnt+1), in LDS/registers
    int v = (tid < nn) ? cnt[tid] + 1 : 0;
    int lane = tid & 63, w = tid >> 6;
    int incl = v;
    #pragma unroll
    for (int o = 1; o < 64; o <<= 1) {
        int u = __shfl_up(incl, o);
        if (lane >= o) incl += u;
    }
    if (lane == 63) wsum[w] = incl;
    __syncthreads();
    if (tid == 0) {
        int run = 0;
        for (int i = 0; i < 4; ++i) { int t = wsum[i]; wsum[i] = run; run += t; }
    }
    __syncthreads();
    int excl = incl - v + wsum[w];
    cur[tid] = excl;
    if (tid < nn) rowptr[n0 + tid] = cb + excl;
    if (bkt == NB - 1 && tid == 0) rowptr[N] = E + N;
    __syncthreads();
    if (csrlen <= OUTCAP) {
        for (int i = tid; i < elen; i += 256) {
            unsigned wd = stage[eb + i];
            int p = atomicAdd(&cur[wd >> 24], 1);
            out[p] = (int)(wd & 0xFFFFFFu);
        }
        __syncthreads();
        if (tid < nn) out[cur[tid]] = n0 + tid;           // self loop at segment end
        __syncthreads();
        for (int i = tid; i < csrlen; i += 256) csr_src[cb + i] = out[i];   // coalesced
    } else {
        // overflow fallback (statistically unreachable)
        for (int i = tid; i < elen; i += 256) {
            unsigned wd = stage[eb + i];
            int p = atomicAdd(&cur[wd >> 24], 1);
            csr_src[cb + p] = (int)(wd & 0xFFFFFFu);
        }
        __syncthreads();
        if (tid < nn) csr_src[cb + cur[tid]] = n0 + tid;
    }
}

// ---------------- GEMM + fused score epilogue; h packed bf16 via LDS flush ----------------
template<int K>
__device__ __forceinline__ void gemm_body(float* smem,
                                          const float* __restrict__ x, const float* __restrict__ W,
                                          const float* __restrict__ asrc, const float* __restrict__ adst,
                                          unsigned* __restrict__ hb, float* __restrict__ es,
                                          float* __restrict__ ed, int N, int bid) {
    constexpr int ROWS = 16;
    constexpr int KP = K + 4;
    constexpr int K4 = K / 4;
    float* Ws = smem;                                  // [64][KP] transposed
    float* xs = smem + 64 * KP;                        // [ROWS][K]
    unsigned* hs = (unsigned*)(smem + 64 * KP + ROWS * K);  // [ROWS*32] packed bf16x2
    int base = bid * ROWS;

    {
        int c = threadIdx.x & 63;
        int q0 = threadIdx.x >> 6;
        #pragma unroll
        for (int it = 0; it < K4 / 4; ++it) {
            int q = q0 + 4 * it;
            float4 v;
            v.x = W[(4 * q + 0) * F + c];
            v.y = W[(4 * q + 1) * F + c];
            v.z = W[(4 * q + 2) * F + c];
            v.w = W[(4 * q + 3) * F + c];
            *(float4*)&Ws[c * KP + 4 * q] = v;
        }
    }
    int nrows = min(ROWS, N - base);
    float4* xs4 = (float4*)xs;
    const float4* x4 = (const float4*)x;
    for (int i = threadIdx.x; i < nrows * K4; i += 256) {
        int r = i / K4, k4 = i - r * K4;
        xs4[r * K4 + k4] = x4[(size_t)(base + r) * K4 + k4];
    }
    __syncthreads();

    int wave = threadIdx.x >> 6, lane = threadIdx.x & 63;
    float as_l = asrc[lane];
    float ad_l = adst[lane];
    const float4* wr = (const float4*)&Ws[lane * KP];
    const float4* xr0 = (const float4*)&xs[(wave + 0) * K];
    const float4* xr1 = (const float4*)&xs[(wave + 4) * K];
    const float4* xr2 = (const float4*)&xs[(wave + 8) * K];
    const float4* xr3 = (const float4*)&xs[(wave + 12) * K];
    float a0 = 0.f, a1 = 0.f, a2 = 0.f, a3 = 0.f;
    #pragma unroll 8
    for (int k4 = 0; k4 < K4; ++k4) {
        float4 wv = wr[k4];
        float4 v0 = xr0[k4], v1 = xr1[k4], v2 = xr2[k4], v3 = xr3[k4];
        a0 = fmaf(v0.x, wv.x, fmaf(v0.y, wv.y, fmaf(v0.z, wv.z, fmaf(v0.w, wv.w, a0))));
        a1 = fmaf(v1.x, wv.x, fmaf(v1.y, wv.y, fmaf(v1.z, wv.z, fmaf(v1.w, wv.w, a1))));
        a2 = fmaf(v2.x, wv.x, fmaf(v2.y, wv.y, fmaf(v2.z, wv.z, fmaf(v2.w, wv.w, a2))));
        a3 = fmaf(v3.x, wv.x, fmaf(v3.y, wv.y, fmaf(v3.z, wv.z, fmaf(v3.w, wv.w, a3))));
    }
    float accs[4] = {a0, a1, a2, a3};
    #pragma unroll
    for (int rr = 0; rr < 4; ++rr) {
        int r = wave + 4 * rr;
        float acc = accs[rr];
        unsigned ub = __float_as_uint(acc);
        unsigned rb = (ub + 0x7FFF + ((ub >> 16) & 1)) >> 16;   // RNE bf16 bits
        unsigned pb = (unsigned)__shfl_xor((int)rb, 1);
        if ((lane & 1) == 0) hs[r * 32 + (lane >> 1)] = (pb << 16) | rb;
        float vs = acc * as_l;
        float vd = acc * ad_l;
        #pragma unroll
        for (int o = 32; o > 0; o >>= 1) {
            vs += __shfl_down(vs, o);
            vd += __shfl_down(vd, o);
        }
        if (lane == 0 && r < nrows) { es[base + r] = vs; ed[base + r] = vd; }
    }
    __syncthreads();
    unsigned* hbase = hb + (size_t)base * 32;
    for (int i = threadIdx.x; i < nrows * 32; i += 256) hbase[i] = hs[i];
}

template<int K>
__global__ void gemm_kernel(const float* __restrict__ x, const float* __restrict__ W,
                            const float* __restrict__ asrc, const float* __restrict__ adst,
                            unsigned* __restrict__ hb, float* __restrict__ es,
                            float* __restrict__ ed, int N) {
    extern __shared__ float smem[];
    gemm_body<K>(smem, x, W, asrc, adst, hb, es, ed, N, blockIdx.x);
}

// ---------------- per-node segment softmax + aggregation (bf16 h gather) ----------------
__device__ __forceinline__ float unpack_h(unsigned pw, int lane) {
    return __uint_as_float((lane & 1) ? (pw & 0xFFFF0000u) : (pw << 16));
}

__global__ void gat_aggregate(const unsigned* __restrict__ hb, const float* __restrict__ es,
                              const float* __restrict__ ed, const int* __restrict__ rowptr,
                              const int* __restrict__ csr_src, const float* __restrict__ bias,
                              float* __restrict__ xout, int N) {
    __shared__ float2 sw[4][64];
    int wave = threadIdx.x >> 6, lane = threadIdx.x & 63;
    int node = blockIdx.x * 4 + wave;
    if (node >= N) return;
    int beg = rowptr[node], end = rowptr[node + 1];
    int cnt = end - beg;
    float edn = ed[node];
    int half = lane >> 1;
    float acc;

    if (cnt <= 64) {
        int s = 0;
        float e = -1e30f;
        if (lane < cnt) {
            s = csr_src[beg + lane];
            float t = es[s] + edn;
            e = t > 0.f ? t : 0.2f * t;
        }
        float m = e;
        #pragma unroll
        for (int o = 32; o > 0; o >>= 1) m = fmaxf(m, __shfl_xor(m, o));
        float w = (lane < cnt) ? __expf(e - m) : 0.f;
        float den = w;
        #pragma unroll
        for (int o = 32; o > 0; o >>= 1) den += __shfl_xor(den, o);
        sw[wave][lane] = make_float2(__int_as_float(s), w);
        float a0 = 0.f, a1 = 0.f, a2 = 0.f, a3 = 0.f;
        int i = 0;
        for (; i + 3 < cnt; i += 4) {
            float2 p0 = sw[wave][i];
            float2 p1 = sw[wave][i + 1];
            float2 p2 = sw[wave][i + 2];
            float2 p3 = sw[wave][i + 3];
            float h0 = unpack_h(hb[(size_t)__float_as_int(p0.x) * 32 + half], lane);
            float h1 = unpack_h(hb[(size_t)__float_as_int(p1.x) * 32 + half], lane);
            float h2 = unpack_h(hb[(size_t)__float_as_int(p2.x) * 32 + half], lane);
            float h3 = unpack_h(hb[(size_t)__float_as_int(p3.x) * 32 + half], lane);
            a0 = fmaf(p0.y, h0, a0);
            a1 = fmaf(p1.y, h1, a1);
            a2 = fmaf(p2.y, h2, a2);
            a3 = fmaf(p3.y, h3, a3);
        }
        for (; i < cnt; ++i) {
            float2 p = sw[wave][i];
            a0 = fmaf(p.y, unpack_h(hb[(size_t)__float_as_int(p.x) * 32 + half], lane), a0);
        }
        acc = ((a0 + a1) + (a2 + a3)) / (den + 1e-16f);
    } else {
        float m = -1e30f;
        for (int j = beg + lane; j < end; j += 64) {
            float e = es[csr_src[j]] + edn;
            e = e > 0.f ? e : 0.2f * e;
            m = fmaxf(m, e);
        }
        #pragma unroll
        for (int o = 32; o > 0; o >>= 1) m = fmaxf(m, __shfl_xor(m, o));
        float a = 0.f, den = 0.f;
        for (int j = beg; j < end; ++j) {
            int s = csr_src[j];
            float e = es[s] + edn;
            e = e > 0.f ? e : 0.2f * e;
            float w = __expf(e - m);
            den += w;
            a = fmaf(w, unpack_h(hb[(size_t)s * 32 + half], lane), a);
        }
        acc = a / (den + 1e-16f);
    }
    float v = acc + bias[lane];
    v = v > 0.f ? v : 0.f;   // relu
    xout[(size_t)node * F + lane] = v;
}

// ---------------- mean pooling: 4 blocks per graph, register accumulate ----------------
__global__ void pool_kernel(const float* __restrict__ x1, const float* __restrict__ x2,
                            const float* __restrict__ x3, const int* __restrict__ gstart,
                            float* __restrict__ pooled) {
    int g = blockIdx.x >> 2;
    int seg = blockIdx.x & 3;
    int f = threadIdx.x;               // 0..191
    int lane = f & 63;
    const float* src = (f < 64) ? x1 : (f < 128) ? x2 : x3;
    int lo = gstart[g], hi = gstart[g + 1];
    int len = hi - lo;
    int chunk = (len + 3) >> 2;
    int b = lo + seg * chunk;
    int e = min(hi, b + chunk);
    float s0 = 0.f, s1 = 0.f, s2 = 0.f, s3 = 0.f;
    int i = b;
    for (; i + 3 < e; i += 4) {
        s0 += src[(size_t)i * F + lane];
        s1 += src[(size_t)(i + 1) * F + lane];
        s2 += src[(size_t)(i + 2) * F + lane];
        s3 += src[(size_t)(i + 3) * F + lane];
    }
    for (; i < e; ++i) s0 += src[(size_t)i * F + lane];
    float s = (s0 + s1) + (s2 + s3);
    atomicAdd(&pooled[g * 192 + f], s);
}

// ---------------- final linear + softmax ----------------
__global__ void head_kernel(const float* __restrict__ pooled, const int* __restrict__ gstart,
                            const float* __restrict__ Wo, const float* __restrict__ bo,
                            float* __restrict__ out) {
    int g = blockIdx.x * blockDim.x + threadIdx.x;
    if (g >= GRAPHS) return;
    int cntg = gstart[g + 1] - gstart[g];
    float inv = 1.0f / fmaxf((float)cntg, 1.0f);
    float acc[CLASSES];
    #pragma unroll
    for (int c = 0; c < CLASSES; ++c) acc[c] = bo[c];
    for (int f = 0; f < 192; ++f) {
        float p = pooled[g * 192 + f] * inv;
        #pragma unroll
        for (int c = 0; c < CLASSES; ++c) acc[c] = fmaf(p, Wo[f * CLASSES + c], acc[c]);
    }
    float mx = acc[0];
    #pragma unroll
    for (int c = 1; c < CLASSES; ++c) mx = fmaxf(mx, acc[c]);
    float s = 0.f;
    #pragma unroll
    for (int c = 0; c < CLASSES; ++c) { acc[c] = __expf(acc[c] - mx); s += acc[c]; }
    float invs = 1.0f / s;
    #pragma unroll
    for (int c = 0; c < CLASSES; ++c) out[g * CLASSES + c] = acc[c] * invs;
}

extern "C" void kernel_launch(void* const* d_in, const int* in_sizes, int n_in,
                              void* d_out, int out_size, void* d_ws, size_t ws_size,
                              hipStream_t stream) {
    const float* x   = (const float*)d_in[0];
    const int* ei    = (const int*)d_in[1];
    const int* batch = (const int*)d_in[2];
    const float* W1  = (const float*)d_in[3];
    const float* a1s = (const float*)d_in[4];
    const float* a1d = (const float*)d_in[5];
    const float* b1  = (const float*)d_in[6];
    const float* W2  = (const float*)d_in[7];
    const float* a2s = (const float*)d_in[8];
    const float* a2d = (const float*)d_in[9];
    const float* b2  = (const float*)d_in[10];
    const float* W3  = (const float*)d_in[11];
    const float* a3s = (const float*)d_in[12];
    const float* a3d = (const float*)d_in[13];
    const float* b3  = (const float*)d_in[14];
    const float* Wo  = (const float*)d_in[15];
    const float* bo  = (const float*)d_in[16];
    float* out = (float*)d_out;

    const int N = in_sizes[2];          // #nodes
    const int E = in_sizes[1] / 2;      // real edges
    const int TOT = E + N;              // with self loops
    const int NB = (N + 255) >> 8;      // buckets (391)
    const int M  = NB * NBLK;           // histogram entries

    char* p = (char*)d_ws;
    auto alloc = [&](size_t bytes) { char* r = p; p += (bytes + 255) & ~(size_t)255; return r; };
    float* x1      = (float*)alloc((size_t)N * F * 4);
    float* x2      = (float*)alloc((size_t)N * F * 4);
    float* x3      = (float*)alloc((size_t)N * F * 4);
    unsigned* hb   = (unsigned*)alloc((size_t)N * 32 * 4);   // bf16x2 packed h
    float* es      = (float*)alloc((size_t)N * 4);
    float* ed      = (float*)alloc((size_t)N * 4);
    int* rowptr    = (int*)alloc((size_t)(N + 1) * 4);
    int* csr_src   = (int*)alloc((size_t)TOT * 4);
    unsigned* stage= (unsigned*)alloc((size_t)E * 4);
    int* hist      = (int*)alloc((size_t)M * 4);
    int* shist     = (int*)alloc((size_t)M * 4);
    int* partial   = (int*)alloc((size_t)SCAN_T * 4);
    float* pooled  = (float*)alloc((size_t)GRAPHS * 192 * 4);
    int* gstart    = (int*)alloc((size_t)(GRAPHS + 1) * 4);

    hipMemsetAsync(pooled, 0, (size_t)GRAPHS * 192 * 4, stream);

    const int GB = (N + 15) / 16;
    const size_t SM128 = (size_t)(64 * 132 + 16 * 128) * 4 + 2048;   // W + x + h-stage
    const size_t SM64  = (size_t)(64 * 68 + 16 * 64) * 4 + 2048;
    int node_blocks = (N + 3) / 4;

    // CSR build: hist -> scan -> binned scatter -> place (derives rowptr; no global atomics)
    hist_gb_kernel<<<NBLK + 3, 256, 0, stream>>>(ei, E, NB, hist, batch, N, gstart);
    hscan_partial<<<SCAN_T / 256, 256, 0, stream>>>(hist, M, NB, partial);
    scan_block<<<1, SCAN_T, 0, stream>>>(partial);
    hscan_final<<<SCAN_T / 256, 256, 0, stream>>>(hist, partial, M, NB, shist);
    scatter3<<<NBLK, 256, 0, stream>>>(ei, E, NB, shist, stage);
    place2<<<NB, 256, 0, stream>>>(stage, shist, rowptr, csr_src, N, E, NB);

    // layer 1
    gemm_kernel<128><<<GB, 256, SM128, stream>>>(x, W1, a1s, a1d, hb, es, ed, N);
    gat_aggregate<<<node_blocks, 256, 0, stream>>>(hb, es, ed, rowptr, csr_src, b1, x1, N);
    // layer 2
    gemm_kernel<64><<<GB, 256, SM64, stream>>>(x1, W2, a2s, a2d, hb, es, ed, N);
    gat_aggregate<<<node_blocks, 256, 0, stream>>>(hb, es, ed, rowptr, csr_src, b2, x2, N);
    // layer 3
    gemm_kernel<64><<<GB, 256, SM64, stream>>>(x2, W3, a3s, a3d, hb, es, ed, N);
    gat_aggregate<<<node_blocks, 256, 0, stream>>>(hb, es, ed, rowptr, csr_src, b3, x3, N);

    // readout
    pool_kernel<<<GRAPHS * 4, 192, 0, stream>>>(x1, x2, x3, gstart, pooled);
    head_kernel<<<(GRAPHS + 255) / 256, 256, 0, stream>>>(pooled, gstart, Wo, bo, out);
}

// Round 9
// 542.155 us; speedup vs baseline: 2.1412x; 1.0735x over previous
//
#include <hip/hip_runtime.h>
#include <hip/hip_bf16.h>

#define F 64
#define GRAPHS 512
#define CLASSES 10
#define SCAN_T 1024
#define NBLK 256       // histogram/scatter blocks (power of 2)
#define OUTCAP 8448    // bucket CSR slots (mean ~4350, sigma ~64 — never overflows)

// ---------------- phase 1: per-block LDS histogram over dst buckets (+gbounds) ----------------
// hist stored BUCKET-MAJOR: hist[bucket*NBLK + blk] — scan order == memory order.
__global__ void hist_gb_kernel(const int* __restrict__ ei, int E, int NB,
                               int* __restrict__ hist,
                               const int* __restrict__ batch, int N, int* __restrict__ gstart) {
    int blk = blockIdx.x, tid = threadIdx.x;
    if (blk < NBLK) {
        __shared__ int lh[512];
        lh[tid] = 0; lh[tid + 256] = 0;
        __syncthreads();
        int chunk = (E + NBLK - 1) / NBLK;
        int b = blk * chunk, e = min(E, b + chunk);
        for (int i = b + tid; i < e; i += 256) atomicAdd(&lh[ei[E + i] >> 8], 1);
        __syncthreads();
        for (int j = tid; j < NB; j += 256) hist[j * NBLK + blk] = lh[j];  // strided, 1-2/thread
    } else {
        int g = (blk - NBLK) * 256 + tid;
        if (g > GRAPHS) return;
        int lo = 0, hi = N;
        while (lo < hi) {
            int mid = (lo + hi) >> 1;
            if (batch[mid] < g) lo = mid + 1; else hi = mid;
        }
        gstart[g] = lo;
    }
}

// ---------------- phase 2: exclusive scan of hist (contiguous: layout == scan order) ------
__global__ void hscan_partial(const int* __restrict__ hist, int M,
                              int* __restrict__ partial) {
    int t = blockIdx.x * blockDim.x + threadIdx.x;   // 0..1023
    int chunk = (M + SCAN_T - 1) / SCAN_T;
    int b = t * chunk, e = min(M, b + chunk);
    int s = 0;
    for (int l = b; l < e; ++l) s += hist[l];
    partial[t] = s;
}

__global__ void scan_block(int* __restrict__ partial) {   // 1 block, 1024 threads
    __shared__ int wsum[16];
    int t = threadIdx.x;
    int lane = t & 63, w = t >> 6;
    int orig = partial[t];
    int v = orig;
    #pragma unroll
    for (int o = 1; o < 64; o <<= 1) {
        int u = __shfl_up(v, o);
        if (lane >= o) v += u;
    }
    if (lane == 63) wsum[w] = v;
    __syncthreads();
    if (t == 0) {
        int run = 0;
        for (int i = 0; i < 16; ++i) { int x = wsum[i]; wsum[i] = run; run += x; }
    }
    __syncthreads();
    v += wsum[w];
    partial[t] = v - orig;   // exclusive prefix
}

__global__ void hscan_final(const int* __restrict__ hist, const int* __restrict__ partial,
                            int M, int* __restrict__ shist) {
    int t = blockIdx.x * blockDim.x + threadIdx.x;
    int chunk = (M + SCAN_T - 1) / SCAN_T;
    int b = t * chunk, e = min(M, b + chunk);
    int run = partial[t];
    for (int l = b; l < e; ++l) {
        int v = hist[l];
        shist[l] = run;
        run += v;
    }
}

// ---------------- phase 3: binned scatter, LDS cursors only (no global atomics) ----------
__global__ void scatter3(const int* __restrict__ ei, int E, int NB,
                         const int* __restrict__ shist, unsigned* __restrict__ stage) {
    __shared__ int offs[512];
    int blk = blockIdx.x, tid = threadIdx.x;
    for (int j = tid; j < NB; j += 256) offs[j] = shist[j * NBLK + blk];
    __syncthreads();
    int chunk = (E + NBLK - 1) / NBLK;
    int b = blk * chunk, e = min(E, b + chunk);
    for (int i = b + tid; i < e; i += 256) {
        int s = ei[i], d = ei[E + i];
        int pos = atomicAdd(&offs[d >> 8], 1);                            // LDS atomic
        stage[pos] = (unsigned)s | ((unsigned)(d & 255) << 24);           // N < 2^24
    }
}

// ---------------- phase 4: per-bucket place; derives rowptr; coalesced CSR flush ---------
__global__ void place2(const unsigned* __restrict__ stage, const int* __restrict__ shist,
                       int* __restrict__ rowptr, int* __restrict__ csr_src,
                       int N, int E, int NB) {
    __shared__ int cnt[256];
    __shared__ int cur[256];
    __shared__ int wsum[4];
    __shared__ int out[OUTCAP];
    int tid = threadIdx.x, bkt = blockIdx.x;
    int n0 = bkt << 8;
    int nn = min(256, N - n0);
    int eb = shist[bkt * NBLK];                           // logical bucket start
    int ee = (bkt == NB - 1) ? E : shist[(bkt + 1) * NBLK];
    int elen = ee - eb;
    int cb = eb + n0;                                     // + one self loop per earlier node
    int csrlen = elen + nn;
    cnt[tid] = 0;
    __syncthreads();
    for (int i = tid; i < elen; i += 256) atomicAdd(&cnt[stage[eb + i] >> 24], 1);
    __syncthreads();
    // 256-wide exclusive scan of per-node segment length (cnt+1), in LDS/registers
    int v = (tid < nn) ? cnt[tid] + 1 : 0;
    int lane = tid & 63, w = tid >> 6;
    int incl = v;
    #pragma unroll
    for (int o = 1; o < 64; o <<= 1) {
        int u = __shfl_up(incl, o);
        if (lane >= o) incl += u;
    }
    if (lane == 63) wsum[w] = incl;
    __syncthreads();
    if (tid == 0) {
        int run = 0;
        for (int i = 0; i < 4; ++i) { int t = wsum[i]; wsum[i] = run; run += t; }
    }
    __syncthreads();
    int excl = incl - v + wsum[w];
    cur[tid] = excl;
    if (tid < nn) rowptr[n0 + tid] = cb + excl;
    if (bkt == NB - 1 && tid == 0) rowptr[N] = E + N;
    __syncthreads();
    if (csrlen <= OUTCAP) {
        for (int i = tid; i < elen; i += 256) {
            unsigned wd = stage[eb + i];
            int p = atomicAdd(&cur[wd >> 24], 1);
            out[p] = (int)(wd & 0xFFFFFFu);
        }
        __syncthreads();
        if (tid < nn) out[cur[tid]] = n0 + tid;           // self loop at segment end
        __syncthreads();
        for (int i = tid; i < csrlen; i += 256) csr_src[cb + i] = out[i];   // coalesced
    } else {
        // overflow fallback (statistically unreachable)
        for (int i = tid; i < elen; i += 256) {
            unsigned wd = stage[eb + i];
            int p = atomicAdd(&cur[wd >> 24], 1);
            csr_src[cb + p] = (int)(wd & 0xFFFFFFu);
        }
        __syncthreads();
        if (tid < nn) csr_src[cb + cur[tid]] = n0 + tid;
    }
}

// ---------------- GEMM + fused score epilogue; h packed bf16 via LDS flush ----------------
template<int K>
__device__ __forceinline__ void gemm_body(float* smem,
                                          const float* __restrict__ x, const float* __restrict__ W,
                                          const float* __restrict__ asrc, const float* __restrict__ adst,
                                          unsigned* __restrict__ hb, float* __restrict__ es,
                                          float* __restrict__ ed, int N, int bid) {
    constexpr int ROWS = 16;
    constexpr int KP = K + 4;
    constexpr int K4 = K / 4;
    float* Ws = smem;                                  // [64][KP] transposed
    float* xs = smem + 64 * KP;                        // [ROWS][K]
    unsigned* hs = (unsigned*)(smem + 64 * KP + ROWS * K);  // [ROWS*32] packed bf16x2
    int base = bid * ROWS;

    {
        int c = threadIdx.x & 63;
        int q0 = threadIdx.x >> 6;
        #pragma unroll
        for (int it = 0; it < K4 / 4; ++it) {
            int q = q0 + 4 * it;
            float4 v;
            v.x = W[(4 * q + 0) * F + c];
            v.y = W[(4 * q + 1) * F + c];
            v.z = W[(4 * q + 2) * F + c];
            v.w = W[(4 * q + 3) * F + c];
            *(float4*)&Ws[c * KP + 4 * q] = v;
        }
    }
    int nrows = min(ROWS, N - base);
    float4* xs4 = (float4*)xs;
    const float4* x4 = (const float4*)x;
    for (int i = threadIdx.x; i < nrows * K4; i += 256) {
        int r = i / K4, k4 = i - r * K4;
        xs4[r * K4 + k4] = x4[(size_t)(base + r) * K4 + k4];
    }
    __syncthreads();

    int wave = threadIdx.x >> 6, lane = threadIdx.x & 63;
    float as_l = asrc[lane];
    float ad_l = adst[lane];
    const float4* wr = (const float4*)&Ws[lane * KP];
    const float4* xr0 = (const float4*)&xs[(wave + 0) * K];
    const float4* xr1 = (const float4*)&xs[(wave + 4) * K];
    const float4* xr2 = (const float4*)&xs[(wave + 8) * K];
    const float4* xr3 = (const float4*)&xs[(wave + 12) * K];
    float a0 = 0.f, a1 = 0.f, a2 = 0.f, a3 = 0.f;
    #pragma unroll 8
    for (int k4 = 0; k4 < K4; ++k4) {
        float4 wv = wr[k4];
        float4 v0 = xr0[k4], v1 = xr1[k4], v2 = xr2[k4], v3 = xr3[k4];
        a0 = fmaf(v0.x, wv.x, fmaf(v0.y, wv.y, fmaf(v0.z, wv.z, fmaf(v0.w, wv.w, a0))));
        a1 = fmaf(v1.x, wv.x, fmaf(v1.y, wv.y, fmaf(v1.z, wv.z, fmaf(v1.w, wv.w, a1))));
        a2 = fmaf(v2.x, wv.x, fmaf(v2.y, wv.y, fmaf(v2.z, wv.z, fmaf(v2.w, wv.w, a2))));
        a3 = fmaf(v3.x, wv.x, fmaf(v3.y, wv.y, fmaf(v3.z, wv.z, fmaf(v3.w, wv.w, a3))));
    }
    float accs[4] = {a0, a1, a2, a3};
    #pragma unroll
    for (int rr = 0; rr < 4; ++rr) {
        int r = wave + 4 * rr;
        float acc = accs[rr];
        unsigned ub = __float_as_uint(acc);
        unsigned rb = (ub + 0x7FFF + ((ub >> 16) & 1)) >> 16;   // RNE bf16 bits
        unsigned pb = (unsigned)__shfl_xor((int)rb, 1);
        if ((lane & 1) == 0) hs[r * 32 + (lane >> 1)] = (pb << 16) | rb;
        float vs = acc * as_l;
        float vd = acc * ad_l;
        #pragma unroll
        for (int o = 32; o > 0; o >>= 1) {
            vs += __shfl_down(vs, o);
            vd += __shfl_down(vd, o);
        }
        if (lane == 0 && r < nrows) { es[base + r] = vs; ed[base + r] = vd; }
    }
    __syncthreads();
    unsigned* hbase = hb + (size_t)base * 32;
    for (int i = threadIdx.x; i < nrows * 32; i += 256) hbase[i] = hs[i];
}

template<int K>
__global__ void gemm_kernel(const float* __restrict__ x, const float* __restrict__ W,
                            const float* __restrict__ asrc, const float* __restrict__ adst,
                            unsigned* __restrict__ hb, float* __restrict__ es,
                            float* __restrict__ ed, int N) {
    extern __shared__ float smem[];
    gemm_body<K>(smem, x, W, asrc, adst, hb, es, ed, N, blockIdx.x);
}

// ---------------- per-node segment softmax + aggregation (bf16 h gather) ----------------
__device__ __forceinline__ float unpack_h(unsigned pw, int lane) {
    return __uint_as_float((lane & 1) ? (pw & 0xFFFF0000u) : (pw << 16));
}

__global__ void gat_aggregate(const unsigned* __restrict__ hb, const float* __restrict__ es,
                              const float* __restrict__ ed, const int* __restrict__ rowptr,
                              const int* __restrict__ csr_src, const float* __restrict__ bias,
                              float* __restrict__ xout, int N) {
    __shared__ float2 sw[4][64];
    int wave = threadIdx.x >> 6, lane = threadIdx.x & 63;
    int node = blockIdx.x * 4 + wave;
    if (node >= N) return;
    int beg = rowptr[node], end = rowptr[node + 1];
    int cnt = end - beg;
    float edn = ed[node];
    int half = lane >> 1;
    float acc;

    if (cnt <= 64) {
        int s = 0;
        float e = -1e30f;
        if (lane < cnt) {
            s = csr_src[beg + lane];
            float t = es[s] + edn;
            e = t > 0.f ? t : 0.2f * t;
        }
        float m = e;
        #pragma unroll
        for (int o = 32; o > 0; o >>= 1) m = fmaxf(m, __shfl_xor(m, o));
        float w = (lane < cnt) ? __expf(e - m) : 0.f;
        float den = w;
        #pragma unroll
        for (int o = 32; o > 0; o >>= 1) den += __shfl_xor(den, o);
        sw[wave][lane] = make_float2(__int_as_float(s), w);
        float a0 = 0.f, a1 = 0.f, a2 = 0.f, a3 = 0.f;
        int i = 0;
        for (; i + 3 < cnt; i += 4) {
            float2 p0 = sw[wave][i];
            float2 p1 = sw[wave][i + 1];
            float2 p2 = sw[wave][i + 2];
            float2 p3 = sw[wave][i + 3];
            float h0 = unpack_h(hb[(size_t)__float_as_int(p0.x) * 32 + half], lane);
            float h1 = unpack_h(hb[(size_t)__float_as_int(p1.x) * 32 + half], lane);
            float h2 = unpack_h(hb[(size_t)__float_as_int(p2.x) * 32 + half], lane);
            float h3 = unpack_h(hb[(size_t)__float_as_int(p3.x) * 32 + half], lane);
            a0 = fmaf(p0.y, h0, a0);
            a1 = fmaf(p1.y, h1, a1);
            a2 = fmaf(p2.y, h2, a2);
            a3 = fmaf(p3.y, h3, a3);
        }
        for (; i < cnt; ++i) {
            float2 p = sw[wave][i];
            a0 = fmaf(p.y, unpack_h(hb[(size_t)__float_as_int(p.x) * 32 + half], lane), a0);
        }
        acc = ((a0 + a1) + (a2 + a3)) / (den + 1e-16f);
    } else {
        float m = -1e30f;
        for (int j = beg + lane; j < end; j += 64) {
            float e = es[csr_src[j]] + edn;
            e = e > 0.f ? e : 0.2f * e;
            m = fmaxf(m, e);
        }
        #pragma unroll
        for (int o = 32; o > 0; o >>= 1) m = fmaxf(m, __shfl_xor(m, o));
        float a = 0.f, den = 0.f;
        for (int j = beg; j < end; ++j) {
            int s = csr_src[j];
            float e = es[s] + edn;
            e = e > 0.f ? e : 0.2f * e;
            float w = __expf(e - m);
            den += w;
            a = fmaf(w, unpack_h(hb[(size_t)s * 32 + half], lane), a);
        }
        acc = a / (den + 1e-16f);
    }
    float v = acc + bias[lane];
    v = v > 0.f ? v : 0.f;   // relu
    xout[(size_t)node * F + lane] = v;
}

// ---------------- mean pooling: 4 blocks per graph, register accumulate ----------------
__global__ void pool_kernel(const float* __restrict__ x1, const float* __restrict__ x2,
                            const float* __restrict__ x3, const int* __restrict__ gstart,
                            float* __restrict__ pooled) {
    int g = blockIdx.x >> 2;
    int seg = blockIdx.x & 3;
    int f = threadIdx.x;               // 0..191
    int lane = f & 63;
    const float* src = (f < 64) ? x1 : (f < 128) ? x2 : x3;
    int lo = gstart[g], hi = gstart[g + 1];
    int len = hi - lo;
    int chunk = (len + 3) >> 2;
    int b = lo + seg * chunk;
    int e = min(hi, b + chunk);
    float s0 = 0.f, s1 = 0.f, s2 = 0.f, s3 = 0.f;
    int i = b;
    for (; i + 3 < e; i += 4) {
        s0 += src[(size_t)i * F + lane];
        s1 += src[(size_t)(i + 1) * F + lane];
        s2 += src[(size_t)(i + 2) * F + lane];
        s3 += src[(size_t)(i + 3) * F + lane];
    }
    for (; i < e; ++i) s0 += src[(size_t)i * F + lane];
    float s = (s0 + s1) + (s2 + s3);
    atomicAdd(&pooled[g * 192 + f], s);
}

// ---------------- final linear + softmax ----------------
__global__ void head_kernel(const float* __restrict__ pooled, const int* __restrict__ gstart,
                            const float* __restrict__ Wo, const float* __restrict__ bo,
                            float* __restrict__ out) {
    int g = blockIdx.x * blockDim.x + threadIdx.x;
    if (g >= GRAPHS) return;
    int cntg = gstart[g + 1] - gstart[g];
    float inv = 1.0f / fmaxf((float)cntg, 1.0f);
    float acc[CLASSES];
    #pragma unroll
    for (int c = 0; c < CLASSES; ++c) acc[c] = bo[c];
    for (int f = 0; f < 192; ++f) {
        float p = pooled[g * 192 + f] * inv;
        #pragma unroll
        for (int c = 0; c < CLASSES; ++c) acc[c] = fmaf(p, Wo[f * CLASSES + c], acc[c]);
    }
    float mx = acc[0];
    #pragma unroll
    for (int c = 1; c < CLASSES; ++c) mx = fmaxf(mx, acc[c]);
    float s = 0.f;
    #pragma unroll
    for (int c = 0; c < CLASSES; ++c) { acc[c] = __expf(acc[c] - mx); s += acc[c]; }
    float invs = 1.0f / s;
    #pragma unroll
    for (int c = 0; c < CLASSES; ++c) out[g * CLASSES + c] = acc[c] * invs;
}

extern "C" void kernel_launch(void* const* d_in, const int* in_sizes, int n_in,
                              void* d_out, int out_size, void* d_ws, size_t ws_size,
                              hipStream_t stream) {
    const float* x   = (const float*)d_in[0];
    const int* ei    = (const int*)d_in[1];
    const int* batch = (const int*)d_in[2];
    const float* W1  = (const float*)d_in[3];
    const float* a1s = (const float*)d_in[4];
    const float* a1d = (const float*)d_in[5];
    const float* b1  = (const float*)d_in[6];
    const float* W2  = (const float*)d_in[7];
    const float* a2s = (const float*)d_in[8];
    const float* a2d = (const float*)d_in[9];
    const float* b2  = (const float*)d_in[10];
    const float* W3  = (const float*)d_in[11];
    const float* a3s = (const float*)d_in[12];
    const float* a3d = (const float*)d_in[13];
    const float* b3  = (const float*)d_in[14];
    const float* Wo  = (const float*)d_in[15];
    const float* bo  = (const float*)d_in[16];
    float* out = (float*)d_out;

    const int N = in_sizes[2];          // #nodes
    const int E = in_sizes[1] / 2;      // real edges
    const int TOT = E + N;              // with self loops
    const int NB = (N + 255) >> 8;      // buckets (391)
    const int M  = NB * NBLK;           // histogram entries (100K)

    char* p = (char*)d_ws;
    auto alloc = [&](size_t bytes) { char* r = p; p += (bytes + 255) & ~(size_t)255; return r; };
    float* x1      = (float*)alloc((size_t)N * F * 4);
    float* x2      = (float*)alloc((size_t)N * F * 4);
    float* x3      = (float*)alloc((size_t)N * F * 4);
    unsigned* hb   = (unsigned*)alloc((size_t)N * 32 * 4);   // bf16x2 packed h
    float* es      = (float*)alloc((size_t)N * 4);
    float* ed      = (float*)alloc((size_t)N * 4);
    int* rowptr    = (int*)alloc((size_t)(N + 1) * 4);
    int* csr_src   = (int*)alloc((size_t)TOT * 4);
    unsigned* stage= (unsigned*)alloc((size_t)E * 4);
    int* hist      = (int*)alloc((size_t)M * 4);
    int* shist     = (int*)alloc((size_t)M * 4);
    int* partial   = (int*)alloc((size_t)SCAN_T * 4);
    float* pooled  = (float*)alloc((size_t)GRAPHS * 192 * 4);
    int* gstart    = (int*)alloc((size_t)(GRAPHS + 1) * 4);

    hipMemsetAsync(pooled, 0, (size_t)GRAPHS * 192 * 4, stream);

    const int GB = (N + 15) / 16;
    const size_t SM128 = (size_t)(64 * 132 + 16 * 128) * 4 + 2048;   // W + x + h-stage
    const size_t SM64  = (size_t)(64 * 68 + 16 * 64) * 4 + 2048;
    int node_blocks = (N + 3) / 4;

    // CSR build: hist -> scan (contiguous layout) -> binned scatter -> place
    hist_gb_kernel<<<NBLK + 3, 256, 0, stream>>>(ei, E, NB, hist, batch, N, gstart);
    hscan_partial<<<SCAN_T / 256, 256, 0, stream>>>(hist, M, partial);
    scan_block<<<1, SCAN_T, 0, stream>>>(partial);
    hscan_final<<<SCAN_T / 256, 256, 0, stream>>>(hist, partial, M, shist);
    scatter3<<<NBLK, 256, 0, stream>>>(ei, E, NB, shist, stage);
    place2<<<NB, 256, 0, stream>>>(stage, shist, rowptr, csr_src, N, E, NB);

    // layer 1
    gemm_kernel<128><<<GB, 256, SM128, stream>>>(x, W1, a1s, a1d, hb, es, ed, N);
    gat_aggregate<<<node_blocks, 256, 0, stream>>>(hb, es, ed, rowptr, csr_src, b1, x1, N);
    // layer 2
    gemm_kernel<64><<<GB, 256, SM64, stream>>>(x1, W2, a2s, a2d, hb, es, ed, N);
    gat_aggregate<<<node_blocks, 256, 0, stream>>>(hb, es, ed, rowptr, csr_src, b2, x2, N);
    // layer 3
    gemm_kernel<64><<<GB, 256, SM64, stream>>>(x2, W3, a3s, a3d, hb, es, ed, N);
    gat_aggregate<<<node_blocks, 256, 0, stream>>>(hb, es, ed, rowptr, csr_src, b3, x3, N);

    // readout
    pool_kernel<<<GRAPHS * 4, 192, 0, stream>>>(x1, x2, x3, gstart, pooled);
    head_kernel<<<(GRAPHS + 255) / 256, 256, 0, stream>>>(pooled, gstart, Wo, bo, out);
}

// Round 10
// 534.003 us; speedup vs baseline: 2.1739x; 1.0153x over previous
//
#include <hip/hip_runtime.h>
#include <hip/hip_bf16.h>

#define F 64
#define GRAPHS 512
#define CLASSES 10
#define SCAN_T 1024
#define NBLK 256       // histogram/scatter blocks (power of 2)
#define OUTCAP 8448    // bucket CSR slots (mean ~4350, sigma ~64 — never overflows)

// ---------------- phase 1: per-block LDS histogram over dst buckets (+gbounds) ----------------
// hist stored BUCKET-MAJOR: hist[bucket*NBLK + blk] — scan order == memory order.
__global__ void hist_gb_kernel(const int* __restrict__ ei, int E, int NB,
                               int* __restrict__ hist,
                               const int* __restrict__ batch, int N, int* __restrict__ gstart) {
    int blk = blockIdx.x, tid = threadIdx.x;
    if (blk < NBLK) {
        __shared__ int lh[512];
        lh[tid] = 0; lh[tid + 256] = 0;
        __syncthreads();
        int chunk = (E + NBLK - 1) / NBLK;
        int b = blk * chunk, e = min(E, b + chunk);
        for (int i = b + tid; i < e; i += 256) atomicAdd(&lh[ei[E + i] >> 8], 1);
        __syncthreads();
        for (int j = tid; j < NB; j += 256) hist[j * NBLK + blk] = lh[j];
    } else {
        int g = (blk - NBLK) * 256 + tid;
        if (g > GRAPHS) return;
        int lo = 0, hi = N;
        while (lo < hi) {
            int mid = (lo + hi) >> 1;
            if (batch[mid] < g) lo = mid + 1; else hi = mid;
        }
        gstart[g] = lo;
    }
}

// ---------------- phase 2: exclusive scan of hist (contiguous layout) ----------------
__global__ void hscan_partial(const int* __restrict__ hist, int M,
                              int* __restrict__ partial) {
    int t = blockIdx.x * blockDim.x + threadIdx.x;
    int chunk = (M + SCAN_T - 1) / SCAN_T;
    int b = t * chunk, e = min(M, b + chunk);
    int s = 0;
    for (int l = b; l < e; ++l) s += hist[l];
    partial[t] = s;
}

__global__ void scan_block(int* __restrict__ partial) {   // 1 block, 1024 threads
    __shared__ int wsum[16];
    int t = threadIdx.x;
    int lane = t & 63, w = t >> 6;
    int orig = partial[t];
    int v = orig;
    #pragma unroll
    for (int o = 1; o < 64; o <<= 1) {
        int u = __shfl_up(v, o);
        if (lane >= o) v += u;
    }
    if (lane == 63) wsum[w] = v;
    __syncthreads();
    if (t == 0) {
        int run = 0;
        for (int i = 0; i < 16; ++i) { int x = wsum[i]; wsum[i] = run; run += x; }
    }
    __syncthreads();
    v += wsum[w];
    partial[t] = v - orig;   // exclusive prefix
}

__global__ void hscan_final(const int* __restrict__ hist, const int* __restrict__ partial,
                            int M, int* __restrict__ shist) {
    int t = blockIdx.x * blockDim.x + threadIdx.x;
    int chunk = (M + SCAN_T - 1) / SCAN_T;
    int b = t * chunk, e = min(M, b + chunk);
    int run = partial[t];
    for (int l = b; l < e; ++l) {
        int v = hist[l];
        shist[l] = run;
        run += v;
    }
}

// ---------------- phase 3: binned scatter, LDS cursors only ----------------
__global__ void scatter3(const int* __restrict__ ei, int E, int NB,
                         const int* __restrict__ shist, unsigned* __restrict__ stage) {
    __shared__ int offs[512];
    int blk = blockIdx.x, tid = threadIdx.x;
    for (int j = tid; j < NB; j += 256) offs[j] = shist[j * NBLK + blk];
    __syncthreads();
    int chunk = (E + NBLK - 1) / NBLK;
    int b = blk * chunk, e = min(E, b + chunk);
    for (int i = b + tid; i < e; i += 256) {
        int s = ei[i], d = ei[E + i];
        int pos = atomicAdd(&offs[d >> 8], 1);
        stage[pos] = (unsigned)s | ((unsigned)(d & 255) << 24);
    }
}

// ---------------- phase 4: per-bucket place; derives rowptr; coalesced CSR flush ---------
__global__ void place2(const unsigned* __restrict__ stage, const int* __restrict__ shist,
                       int* __restrict__ rowptr, int* __restrict__ csr_src,
                       int N, int E, int NB) {
    __shared__ int cnt[256];
    __shared__ int cur[256];
    __shared__ int wsum[4];
    __shared__ int out[OUTCAP];
    int tid = threadIdx.x, bkt = blockIdx.x;
    int n0 = bkt << 8;
    int nn = min(256, N - n0);
    int eb = shist[bkt * NBLK];
    int ee = (bkt == NB - 1) ? E : shist[(bkt + 1) * NBLK];
    int elen = ee - eb;
    int cb = eb + n0;
    int csrlen = elen + nn;
    cnt[tid] = 0;
    __syncthreads();
    for (int i = tid; i < elen; i += 256) atomicAdd(&cnt[stage[eb + i] >> 24], 1);
    __syncthreads();
    int v = (tid < nn) ? cnt[tid] + 1 : 0;
    int lane = tid & 63, w = tid >> 6;
    int incl = v;
    #pragma unroll
    for (int o = 1; o < 64; o <<= 1) {
        int u = __shfl_up(incl, o);
        if (lane >= o) incl += u;
    }
    if (lane == 63) wsum[w] = incl;
    __syncthreads();
    if (tid == 0) {
        int run = 0;
        for (int i = 0; i < 4; ++i) { int t = wsum[i]; wsum[i] = run; run += t; }
    }
    __syncthreads();
    int excl = incl - v + wsum[w];
    cur[tid] = excl;
    if (tid < nn) rowptr[n0 + tid] = cb + excl;
    if (bkt == NB - 1 && tid == 0) rowptr[N] = E + N;
    __syncthreads();
    if (csrlen <= OUTCAP) {
        for (int i = tid; i < elen; i += 256) {
            unsigned wd = stage[eb + i];
            int p = atomicAdd(&cur[wd >> 24], 1);
            out[p] = (int)(wd & 0xFFFFFFu);
        }
        __syncthreads();
        if (tid < nn) out[cur[tid]] = n0 + tid;
        __syncthreads();
        for (int i = tid; i < csrlen; i += 256) csr_src[cb + i] = out[i];
    } else {
        for (int i = tid; i < elen; i += 256) {
            unsigned wd = stage[eb + i];
            int p = atomicAdd(&cur[wd >> 24], 1);
            csr_src[cb + p] = (int)(wd & 0xFFFFFFu);
        }
        __syncthreads();
        if (tid < nn) csr_src[cb + cur[tid]] = n0 + tid;
    }
}

// ---------------- layer-1 GEMM (K=128) + fused score epilogue; bf16 h via LDS flush -------
template<int K>
__global__ void gemm_kernel(const float* __restrict__ x, const float* __restrict__ W,
                            const float* __restrict__ asrc, const float* __restrict__ adst,
                            unsigned* __restrict__ hb, float* __restrict__ es,
                            float* __restrict__ ed, int N) {
    extern __shared__ float smem[];
    constexpr int ROWS = 16;
    constexpr int KP = K + 4;
    constexpr int K4 = K / 4;
    float* Ws = smem;
    float* xs = smem + 64 * KP;
    unsigned* hs = (unsigned*)(smem + 64 * KP + ROWS * K);
    int base = blockIdx.x * ROWS;

    {
        int c = threadIdx.x & 63;
        int q0 = threadIdx.x >> 6;
        #pragma unroll
        for (int it = 0; it < K4 / 4; ++it) {
            int q = q0 + 4 * it;
            float4 v;
            v.x = W[(4 * q + 0) * F + c];
            v.y = W[(4 * q + 1) * F + c];
            v.z = W[(4 * q + 2) * F + c];
            v.w = W[(4 * q + 3) * F + c];
            *(float4*)&Ws[c * KP + 4 * q] = v;
        }
    }
    int nrows = min(ROWS, N - base);
    float4* xs4 = (float4*)xs;
    const float4* x4 = (const float4*)x;
    for (int i = threadIdx.x; i < nrows * K4; i += 256) {
        int r = i / K4, k4 = i - r * K4;
        xs4[r * K4 + k4] = x4[(size_t)(base + r) * K4 + k4];
    }
    __syncthreads();

    int wave = threadIdx.x >> 6, lane = threadIdx.x & 63;
    float as_l = asrc[lane];
    float ad_l = adst[lane];
    const float4* wr = (const float4*)&Ws[lane * KP];
    const float4* xr0 = (const float4*)&xs[(wave + 0) * K];
    const float4* xr1 = (const float4*)&xs[(wave + 4) * K];
    const float4* xr2 = (const float4*)&xs[(wave + 8) * K];
    const float4* xr3 = (const float4*)&xs[(wave + 12) * K];
    float a0 = 0.f, a1 = 0.f, a2 = 0.f, a3 = 0.f;
    #pragma unroll 8
    for (int k4 = 0; k4 < K4; ++k4) {
        float4 wv = wr[k4];
        float4 v0 = xr0[k4], v1 = xr1[k4], v2 = xr2[k4], v3 = xr3[k4];
        a0 = fmaf(v0.x, wv.x, fmaf(v0.y, wv.y, fmaf(v0.z, wv.z, fmaf(v0.w, wv.w, a0))));
        a1 = fmaf(v1.x, wv.x, fmaf(v1.y, wv.y, fmaf(v1.z, wv.z, fmaf(v1.w, wv.w, a1))));
        a2 = fmaf(v2.x, wv.x, fmaf(v2.y, wv.y, fmaf(v2.z, wv.z, fmaf(v2.w, wv.w, a2))));
        a3 = fmaf(v3.x, wv.x, fmaf(v3.y, wv.y, fmaf(v3.z, wv.z, fmaf(v3.w, wv.w, a3))));
    }
    float accs[4] = {a0, a1, a2, a3};
    #pragma unroll
    for (int rr = 0; rr < 4; ++rr) {
        int r = wave + 4 * rr;
        float acc = accs[rr];
        unsigned ub = __float_as_uint(acc);
        unsigned rb = (ub + 0x7FFF + ((ub >> 16) & 1)) >> 16;   // RNE bf16 bits
        unsigned pb = (unsigned)__shfl_xor((int)rb, 1);
        if ((lane & 1) == 0) hs[r * 32 + (lane >> 1)] = (pb << 16) | rb;
        float vs = acc * as_l;
        float vd = acc * ad_l;
        #pragma unroll
        for (int o = 32; o > 0; o >>= 1) {
            vs += __shfl_down(vs, o);
            vd += __shfl_down(vd, o);
        }
        if (lane == 0 && r < nrows) { es[base + r] = vs; ed[base + r] = vd; }
    }
    __syncthreads();
    unsigned* hbase = hb + (size_t)base * 32;
    for (int i = threadIdx.x; i < nrows * 32; i += 256) hbase[i] = hs[i];
}

// ---------------- aggregate (+ optional fused next-layer GEMM epilogue) ----------------
// Block owns 8 nodes (2 per wave). FUSE: after producing the fp32 x-row in registers,
// compute hnext = xrow @ Wn per-lane (Wn transposed in LDS, broadcast xrow reads),
// es/ed via shuffle, packed-bf16 rows staged in LDS and flushed as one contiguous
// 1KB full-wave store (partial-wave dword stores write-around to HBM — R5 lesson).
__device__ __forceinline__ float unpack_h(unsigned pw, int lane) {
    return __uint_as_float((lane & 1) ? (pw & 0xFFFF0000u) : (pw << 16));
}

template<bool FUSE>
__global__ void gat_agg_fused(const unsigned* __restrict__ hb_in, const float* __restrict__ es_in,
                              const float* __restrict__ ed_in, const int* __restrict__ rowptr,
                              const int* __restrict__ csr_src, const float* __restrict__ bias,
                              const float* __restrict__ Wn, const float* __restrict__ ans,
                              const float* __restrict__ and_,
                              float* __restrict__ xout, unsigned* __restrict__ hb_out,
                              float* __restrict__ es_out, float* __restrict__ ed_out, int N) {
    extern __shared__ float smem[];
    constexpr int KP = 68;
    float* Ws = smem;                                        // [64][68] (FUSE only)
    float2* sw = (float2*)(smem + (FUSE ? 64 * KP : 0));     // [4][64]
    float* xrow = (float*)((char*)sw + 2048);                // [4][64] (FUSE only)
    unsigned* hpack = (unsigned*)((char*)xrow + 1024);       // [8][32] (FUSE only)

    int wave = threadIdx.x >> 6, lane = threadIdx.x & 63;
    int base8 = blockIdx.x * 8;
    int half = lane >> 1;

    float as_l = 0.f, ad_l = 0.f;
    if (FUSE) {
        as_l = ans[lane];
        ad_l = and_[lane];
        int c = threadIdx.x & 63;
        int q0 = threadIdx.x >> 6;
        #pragma unroll
        for (int it = 0; it < 4; ++it) {
            int q = q0 + 4 * it;
            float4 v;
            v.x = Wn[(4 * q + 0) * F + c];
            v.y = Wn[(4 * q + 1) * F + c];
            v.z = Wn[(4 * q + 2) * F + c];
            v.w = Wn[(4 * q + 3) * F + c];
            *(float4*)&Ws[c * KP + 4 * q] = v;
        }
        __syncthreads();
    }

    #pragma unroll
    for (int rr = 0; rr < 2; ++rr) {
        int node = base8 + wave + 4 * rr;
        if (node < N) {
            int beg = rowptr[node], end = rowptr[node + 1];
            int cnt = end - beg;
            float edn = ed_in[node];
            float acc;
            if (cnt <= 64) {
                int s = 0;
                float e = -1e30f;
                if (lane < cnt) {
                    s = csr_src[beg + lane];
                    float t = es_in[s] + edn;
                    e = t > 0.f ? t : 0.2f * t;
                }
                float m = e;
                #pragma unroll
                for (int o = 32; o > 0; o >>= 1) m = fmaxf(m, __shfl_xor(m, o));
                float w = (lane < cnt) ? __expf(e - m) : 0.f;
                float den = w;
                #pragma unroll
                for (int o = 32; o > 0; o >>= 1) den += __shfl_xor(den, o);
                sw[wave * 64 + lane] = make_float2(__int_as_float(s), w);
                float a0 = 0.f, a1 = 0.f, a2 = 0.f, a3 = 0.f;
                int i = 0;
                for (; i + 3 < cnt; i += 4) {
                    float2 p0 = sw[wave * 64 + i];
                    float2 p1 = sw[wave * 64 + i + 1];
                    float2 p2 = sw[wave * 64 + i + 2];
                    float2 p3 = sw[wave * 64 + i + 3];
                    float h0 = unpack_h(hb_in[(size_t)__float_as_int(p0.x) * 32 + half], lane);
                    float h1 = unpack_h(hb_in[(size_t)__float_as_int(p1.x) * 32 + half], lane);
                    float h2 = unpack_h(hb_in[(size_t)__float_as_int(p2.x) * 32 + half], lane);
                    float h3 = unpack_h(hb_in[(size_t)__float_as_int(p3.x) * 32 + half], lane);
                    a0 = fmaf(p0.y, h0, a0);
                    a1 = fmaf(p1.y, h1, a1);
                    a2 = fmaf(p2.y, h2, a2);
                    a3 = fmaf(p3.y, h3, a3);
                }
                for (; i < cnt; ++i) {
                    float2 p = sw[wave * 64 + i];
                    a0 = fmaf(p.y, unpack_h(hb_in[(size_t)__float_as_int(p.x) * 32 + half], lane), a0);
                }
                acc = ((a0 + a1) + (a2 + a3)) / (den + 1e-16f);
            } else {
                float m = -1e30f;
                for (int j = beg + lane; j < end; j += 64) {
                    float e = es_in[csr_src[j]] + edn;
                    e = e > 0.f ? e : 0.2f * e;
                    m = fmaxf(m, e);
                }
                #pragma unroll
                for (int o = 32; o > 0; o >>= 1) m = fmaxf(m, __shfl_xor(m, o));
                float a = 0.f, den = 0.f;
                for (int j = beg; j < end; ++j) {
                    int s = csr_src[j];
                    float e = es_in[s] + edn;
                    e = e > 0.f ? e : 0.2f * e;
                    float w = __expf(e - m);
                    den += w;
                    a = fmaf(w, unpack_h(hb_in[(size_t)s * 32 + half], lane), a);
                }
                acc = a / (den + 1e-16f);
            }
            float v = acc + bias[lane];
            v = v > 0.f ? v : 0.f;   // relu
            xout[(size_t)node * F + lane] = v;

            if (FUSE) {
                xrow[wave * 64 + lane] = v;
                const float4* xv4 = (const float4*)&xrow[wave * 64];
                const float4* wv4 = (const float4*)&Ws[lane * KP];
                float a0 = 0.f, a1 = 0.f, a2 = 0.f, a3 = 0.f;
                #pragma unroll
                for (int k4 = 0; k4 < 16; ++k4) {
                    float4 xv = xv4[k4];
                    float4 wv = wv4[k4];
                    a0 = fmaf(xv.x, wv.x, a0);
                    a1 = fmaf(xv.y, wv.y, a1);
                    a2 = fmaf(xv.z, wv.z, a2);
                    a3 = fmaf(xv.w, wv.w, a3);
                }
                float hacc = (a0 + a1) + (a2 + a3);
                float vs = hacc * as_l;
                float vd = hacc * ad_l;
                #pragma unroll
                for (int o = 32; o > 0; o >>= 1) {
                    vs += __shfl_down(vs, o);
                    vd += __shfl_down(vd, o);
                }
                if (lane == 0) { es_out[node] = vs; ed_out[node] = vd; }
                unsigned ub = __float_as_uint(hacc);
                unsigned rb = (ub + 0x7FFF + ((ub >> 16) & 1)) >> 16;
                unsigned pb = (unsigned)__shfl_xor((int)rb, 1);
                if ((lane & 1) == 0) hpack[(wave + 4 * rr) * 32 + (lane >> 1)] = (pb << 16) | rb;
            }
        }
    }
    if (FUSE) {
        __syncthreads();
        int nrows = min(8, N - base8);
        unsigned* hbase = hb_out + (size_t)base8 * 32;
        for (int i = threadIdx.x; i < nrows * 32; i += 256) hbase[i] = hpack[i];
    }
}

// ---------------- mean pooling ----------------
__global__ void pool_kernel(const float* __restrict__ x1, const float* __restrict__ x2,
                            const float* __restrict__ x3, const int* __restrict__ gstart,
                            float* __restrict__ pooled) {
    int g = blockIdx.x >> 2;
    int seg = blockIdx.x & 3;
    int f = threadIdx.x;
    int lane = f & 63;
    const float* src = (f < 64) ? x1 : (f < 128) ? x2 : x3;
    int lo = gstart[g], hi = gstart[g + 1];
    int len = hi - lo;
    int chunk = (len + 3) >> 2;
    int b = lo + seg * chunk;
    int e = min(hi, b + chunk);
    float s0 = 0.f, s1 = 0.f, s2 = 0.f, s3 = 0.f;
    int i = b;
    for (; i + 3 < e; i += 4) {
        s0 += src[(size_t)i * F + lane];
        s1 += src[(size_t)(i + 1) * F + lane];
        s2 += src[(size_t)(i + 2) * F + lane];
        s3 += src[(size_t)(i + 3) * F + lane];
    }
    for (; i < e; ++i) s0 += src[(size_t)i * F + lane];
    float s = (s0 + s1) + (s2 + s3);
    atomicAdd(&pooled[g * 192 + f], s);
}

// ---------------- final linear + softmax ----------------
__global__ void head_kernel(const float* __restrict__ pooled, const int* __restrict__ gstart,
                            const float* __restrict__ Wo, const float* __restrict__ bo,
                            float* __restrict__ out) {
    int g = blockIdx.x * blockDim.x + threadIdx.x;
    if (g >= GRAPHS) return;
    int cntg = gstart[g + 1] - gstart[g];
    float inv = 1.0f / fmaxf((float)cntg, 1.0f);
    float acc[CLASSES];
    #pragma unroll
    for (int c = 0; c < CLASSES; ++c) acc[c] = bo[c];
    for (int f = 0; f < 192; ++f) {
        float p = pooled[g * 192 + f] * inv;
        #pragma unroll
        for (int c = 0; c < CLASSES; ++c) acc[c] = fmaf(p, Wo[f * CLASSES + c], acc[c]);
    }
    float mx = acc[0];
    #pragma unroll
    for (int c = 1; c < CLASSES; ++c) mx = fmaxf(mx, acc[c]);
    float s = 0.f;
    #pragma unroll
    for (int c = 0; c < CLASSES; ++c) { acc[c] = __expf(acc[c] - mx); s += acc[c]; }
    float invs = 1.0f / s;
    #pragma unroll
    for (int c = 0; c < CLASSES; ++c) out[g * CLASSES + c] = acc[c] * invs;
}

extern "C" void kernel_launch(void* const* d_in, const int* in_sizes, int n_in,
                              void* d_out, int out_size, void* d_ws, size_t ws_size,
                              hipStream_t stream) {
    const float* x   = (const float*)d_in[0];
    const int* ei    = (const int*)d_in[1];
    const int* batch = (const int*)d_in[2];
    const float* W1  = (const float*)d_in[3];
    const float* a1s = (const float*)d_in[4];
    const float* a1d = (const float*)d_in[5];
    const float* b1  = (const float*)d_in[6];
    const float* W2  = (const float*)d_in[7];
    const float* a2s = (const float*)d_in[8];
    const float* a2d = (const float*)d_in[9];
    const float* b2  = (const float*)d_in[10];
    const float* W3  = (const float*)d_in[11];
    const float* a3s = (const float*)d_in[12];
    const float* a3d = (const float*)d_in[13];
    const float* b3  = (const float*)d_in[14];
    const float* Wo  = (const float*)d_in[15];
    const float* bo  = (const float*)d_in[16];
    float* out = (float*)d_out;

    const int N = in_sizes[2];
    const int E = in_sizes[1] / 2;
    const int TOT = E + N;
    const int NB = (N + 255) >> 8;
    const int M  = NB * NBLK;

    char* p = (char*)d_ws;
    auto alloc = [&](size_t bytes) { char* r = p; p += (bytes + 255) & ~(size_t)255; return r; };
    float* x1      = (float*)alloc((size_t)N * F * 4);
    float* x2      = (float*)alloc((size_t)N * F * 4);
    float* x3      = (float*)alloc((size_t)N * F * 4);
    unsigned* hbA  = (unsigned*)alloc((size_t)N * 32 * 4);
    unsigned* hbB  = (unsigned*)alloc((size_t)N * 32 * 4);
    float* esA     = (float*)alloc((size_t)N * 4);
    float* edA     = (float*)alloc((size_t)N * 4);
    float* esB     = (float*)alloc((size_t)N * 4);
    float* edB     = (float*)alloc((size_t)N * 4);
    int* rowptr    = (int*)alloc((size_t)(N + 1) * 4);
    int* csr_src   = (int*)alloc((size_t)TOT * 4);
    unsigned* stage= (unsigned*)alloc((size_t)E * 4);
    int* hist      = (int*)alloc((size_t)M * 4);
    int* shist     = (int*)alloc((size_t)M * 4);
    int* partial   = (int*)alloc((size_t)SCAN_T * 4);
    float* pooled  = (float*)alloc((size_t)GRAPHS * 192 * 4);
    int* gstart    = (int*)alloc((size_t)(GRAPHS + 1) * 4);

    hipMemsetAsync(pooled, 0, (size_t)GRAPHS * 192 * 4, stream);

    const int GB = (N + 15) / 16;
    const size_t SM128 = (size_t)(64 * 132 + 16 * 128) * 4 + 2048;
    const size_t SMF   = (size_t)(64 * 68) * 4 + 2048 + 1024 + 1024;   // fused agg: 21.5 KB
    const size_t SMNF  = 2048 + 1024 + 1024;                            // plain agg
    int agg_blocks = (N + 7) / 8;

    // CSR build
    hist_gb_kernel<<<NBLK + 3, 256, 0, stream>>>(ei, E, NB, hist, batch, N, gstart);
    hscan_partial<<<SCAN_T / 256, 256, 0, stream>>>(hist, M, partial);
    scan_block<<<1, SCAN_T, 0, stream>>>(partial);
    hscan_final<<<SCAN_T / 256, 256, 0, stream>>>(hist, partial, M, shist);
    scatter3<<<NBLK, 256, 0, stream>>>(ei, E, NB, shist, stage);
    place2<<<NB, 256, 0, stream>>>(stage, shist, rowptr, csr_src, N, E, NB);

    // layer 1 GEMM (K=128)
    gemm_kernel<128><<<GB, 256, SM128, stream>>>(x, W1, a1s, a1d, hbA, esA, edA, N);
    // agg1 + fused gemm2 -> x1, hbB/esB/edB
    gat_agg_fused<true><<<agg_blocks, 256, SMF, stream>>>(hbA, esA, edA, rowptr, csr_src, b1,
                                                          W2, a2s, a2d, x1, hbB, esB, edB, N);
    // agg2 + fused gemm3 -> x2, hbA/esA/edA (hbA free after agg1)
    gat_agg_fused<true><<<agg_blocks, 256, SMF, stream>>>(hbB, esB, edB, rowptr, csr_src, b2,
                                                          W3, a3s, a3d, x2, hbA, esA, edA, N);
    // agg3 (no fusion) -> x3
    gat_agg_fused<false><<<agg_blocks, 256, SMNF, stream>>>(hbA, esA, edA, rowptr, csr_src, b3,
                                                            nullptr, nullptr, nullptr,
                                                            x3, nullptr, nullptr, nullptr, N);

    // readout
    pool_kernel<<<GRAPHS * 4, 192, 0, stream>>>(x1, x2, x3, gstart, pooled);
    head_kernel<<<(GRAPHS + 255) / 256, 256, 0, stream>>>(pooled, gstart, Wo, bo, out);
}

// Round 11
// 481.592 us; speedup vs baseline: 2.4105x; 1.1088x over previous
//
#include <hip/hip_runtime.h>
#include <hip/hip_bf16.h>

#define F 64
#define GRAPHS 512
#define CLASSES 10
#define SCAN_T 1024
#define NBLK 256       // histogram/scatter blocks (power of 2)
#define OUTCAP 8448    // bucket CSR slots (mean ~4350, sigma ~64 — never overflows)

// ---------------- phase 1: per-block LDS histogram over dst buckets (+gbounds) ----------------
__global__ void hist_gb_kernel(const int* __restrict__ ei, int E, int NB,
                               int* __restrict__ hist,
                               const int* __restrict__ batch, int N, int* __restrict__ gstart) {
    int blk = blockIdx.x, tid = threadIdx.x;
    if (blk < NBLK) {
        __shared__ int lh[512];
        lh[tid] = 0; lh[tid + 256] = 0;
        __syncthreads();
        int chunk = (E + NBLK - 1) / NBLK;
        int b = blk * chunk, e = min(E, b + chunk);
        for (int i = b + tid; i < e; i += 256) atomicAdd(&lh[ei[E + i] >> 8], 1);
        __syncthreads();
        for (int j = tid; j < NB; j += 256) hist[j * NBLK + blk] = lh[j];
    } else {
        int g = (blk - NBLK) * 256 + tid;
        if (g > GRAPHS) return;
        int lo = 0, hi = N;
        while (lo < hi) {
            int mid = (lo + hi) >> 1;
            if (batch[mid] < g) lo = mid + 1; else hi = mid;
        }
        gstart[g] = lo;
    }
}

// ---------------- phase 2: exclusive scan of hist (contiguous layout) ----------------
__global__ void hscan_partial(const int* __restrict__ hist, int M,
                              int* __restrict__ partial) {
    int t = blockIdx.x * blockDim.x + threadIdx.x;
    int chunk = (M + SCAN_T - 1) / SCAN_T;
    int b = t * chunk, e = min(M, b + chunk);
    int s = 0;
    for (int l = b; l < e; ++l) s += hist[l];
    partial[t] = s;
}

__global__ void scan_block(int* __restrict__ partial) {   // 1 block, 1024 threads
    __shared__ int wsum[16];
    int t = threadIdx.x;
    int lane = t & 63, w = t >> 6;
    int orig = partial[t];
    int v = orig;
    #pragma unroll
    for (int o = 1; o < 64; o <<= 1) {
        int u = __shfl_up(v, o);
        if (lane >= o) v += u;
    }
    if (lane == 63) wsum[w] = v;
    __syncthreads();
    if (t == 0) {
        int run = 0;
        for (int i = 0; i < 16; ++i) { int x = wsum[i]; wsum[i] = run; run += x; }
    }
    __syncthreads();
    v += wsum[w];
    partial[t] = v - orig;   // exclusive prefix
}

__global__ void hscan_final(const int* __restrict__ hist, const int* __restrict__ partial,
                            int M, int* __restrict__ shist) {
    int t = blockIdx.x * blockDim.x + threadIdx.x;
    int chunk = (M + SCAN_T - 1) / SCAN_T;
    int b = t * chunk, e = min(M, b + chunk);
    int run = partial[t];
    for (int l = b; l < e; ++l) {
        int v = hist[l];
        shist[l] = run;
        run += v;
    }
}

// ---------------- phase 3: binned scatter, LDS cursors only ----------------
__global__ void scatter3(const int* __restrict__ ei, int E, int NB,
                         const int* __restrict__ shist, unsigned* __restrict__ stage) {
    __shared__ int offs[512];
    int blk = blockIdx.x, tid = threadIdx.x;
    for (int j = tid; j < NB; j += 256) offs[j] = shist[j * NBLK + blk];
    __syncthreads();
    int chunk = (E + NBLK - 1) / NBLK;
    int b = blk * chunk, e = min(E, b + chunk);
    for (int i = b + tid; i < e; i += 256) {
        int s = ei[i], d = ei[E + i];
        int pos = atomicAdd(&offs[d >> 8], 1);
        stage[pos] = (unsigned)s | ((unsigned)(d & 255) << 24);
    }
}

// ---------------- phase 4: per-bucket place; derives rowptr; coalesced CSR flush ---------
__global__ void place2(const unsigned* __restrict__ stage, const int* __restrict__ shist,
                       int* __restrict__ rowptr, int* __restrict__ csr_src,
                       int N, int E, int NB) {
    __shared__ int cnt[256];
    __shared__ int cur[256];
    __shared__ int wsum[4];
    __shared__ int out[OUTCAP];
    int tid = threadIdx.x, bkt = blockIdx.x;
    int n0 = bkt << 8;
    int nn = min(256, N - n0);
    int eb = shist[bkt * NBLK];
    int ee = (bkt == NB - 1) ? E : shist[(bkt + 1) * NBLK];
    int elen = ee - eb;
    int cb = eb + n0;
    int csrlen = elen + nn;
    cnt[tid] = 0;
    __syncthreads();
    for (int i = tid; i < elen; i += 256) atomicAdd(&cnt[stage[eb + i] >> 24], 1);
    __syncthreads();
    int v = (tid < nn) ? cnt[tid] + 1 : 0;
    int lane = tid & 63, w = tid >> 6;
    int incl = v;
    #pragma unroll
    for (int o = 1; o < 64; o <<= 1) {
        int u = __shfl_up(incl, o);
        if (lane >= o) incl += u;
    }
    if (lane == 63) wsum[w] = incl;
    __syncthreads();
    if (tid == 0) {
        int run = 0;
        for (int i = 0; i < 4; ++i) { int t = wsum[i]; wsum[i] = run; run += t; }
    }
    __syncthreads();
    int excl = incl - v + wsum[w];
    cur[tid] = excl;
    if (tid < nn) rowptr[n0 + tid] = cb + excl;
    if (bkt == NB - 1 && tid == 0) rowptr[N] = E + N;
    __syncthreads();
    if (csrlen <= OUTCAP) {
        for (int i = tid; i < elen; i += 256) {
            unsigned wd = stage[eb + i];
            int p = atomicAdd(&cur[wd >> 24], 1);
            out[p] = (int)(wd & 0xFFFFFFu);
        }
        __syncthreads();
        if (tid < nn) out[cur[tid]] = n0 + tid;
        __syncthreads();
        for (int i = tid; i < csrlen; i += 256) csr_src[cb + i] = out[i];
    } else {
        for (int i = tid; i < elen; i += 256) {
            unsigned wd = stage[eb + i];
            int p = atomicAdd(&cur[wd >> 24], 1);
            csr_src[cb + p] = (int)(wd & 0xFFFFFFu);
        }
        __syncthreads();
        if (tid < nn) csr_src[cb + cur[tid]] = n0 + tid;
    }
}

// ---------------- layer-1 GEMM (K=128) + fused score epilogue; bf16 h via LDS flush -------
template<int K>
__global__ void gemm_kernel(const float* __restrict__ x, const float* __restrict__ W,
                            const float* __restrict__ asrc, const float* __restrict__ adst,
                            unsigned* __restrict__ hb, float* __restrict__ es,
                            float* __restrict__ ed, int N) {
    extern __shared__ float smem[];
    constexpr int ROWS = 16;
    constexpr int KP = K + 4;
    constexpr int K4 = K / 4;
    float* Ws = smem;
    float* xs = smem + 64 * KP;
    unsigned* hs = (unsigned*)(smem + 64 * KP + ROWS * K);
    int base = blockIdx.x * ROWS;

    {
        int c = threadIdx.x & 63;
        int q0 = threadIdx.x >> 6;
        #pragma unroll
        for (int it = 0; it < K4 / 4; ++it) {
            int q = q0 + 4 * it;
            float4 v;
            v.x = W[(4 * q + 0) * F + c];
            v.y = W[(4 * q + 1) * F + c];
            v.z = W[(4 * q + 2) * F + c];
            v.w = W[(4 * q + 3) * F + c];
            *(float4*)&Ws[c * KP + 4 * q] = v;
        }
    }
    int nrows = min(ROWS, N - base);
    float4* xs4 = (float4*)xs;
    const float4* x4 = (const float4*)x;
    for (int i = threadIdx.x; i < nrows * K4; i += 256) {
        int r = i / K4, k4 = i - r * K4;
        xs4[r * K4 + k4] = x4[(size_t)(base + r) * K4 + k4];
    }
    __syncthreads();

    int wave = threadIdx.x >> 6, lane = threadIdx.x & 63;
    float as_l = asrc[lane];
    float ad_l = adst[lane];
    const float4* wr = (const float4*)&Ws[lane * KP];
    const float4* xr0 = (const float4*)&xs[(wave + 0) * K];
    const float4* xr1 = (const float4*)&xs[(wave + 4) * K];
    const float4* xr2 = (const float4*)&xs[(wave + 8) * K];
    const float4* xr3 = (const float4*)&xs[(wave + 12) * K];
    float a0 = 0.f, a1 = 0.f, a2 = 0.f, a3 = 0.f;
    #pragma unroll 8
    for (int k4 = 0; k4 < K4; ++k4) {
        float4 wv = wr[k4];
        float4 v0 = xr0[k4], v1 = xr1[k4], v2 = xr2[k4], v3 = xr3[k4];
        a0 = fmaf(v0.x, wv.x, fmaf(v0.y, wv.y, fmaf(v0.z, wv.z, fmaf(v0.w, wv.w, a0))));
        a1 = fmaf(v1.x, wv.x, fmaf(v1.y, wv.y, fmaf(v1.z, wv.z, fmaf(v1.w, wv.w, a1))));
        a2 = fmaf(v2.x, wv.x, fmaf(v2.y, wv.y, fmaf(v2.z, wv.z, fmaf(v2.w, wv.w, a2))));
        a3 = fmaf(v3.x, wv.x, fmaf(v3.y, wv.y, fmaf(v3.z, wv.z, fmaf(v3.w, wv.w, a3))));
    }
    float accs[4] = {a0, a1, a2, a3};
    #pragma unroll
    for (int rr = 0; rr < 4; ++rr) {
        int r = wave + 4 * rr;
        float acc = accs[rr];
        unsigned ub = __float_as_uint(acc);
        unsigned rb = (ub + 0x7FFF + ((ub >> 16) & 1)) >> 16;   // RNE bf16 bits
        unsigned pb = (unsigned)__shfl_xor((int)rb, 1);
        if ((lane & 1) == 0) hs[r * 32 + (lane >> 1)] = (pb << 16) | rb;
        float vs = acc * as_l;
        float vd = acc * ad_l;
        #pragma unroll
        for (int o = 32; o > 0; o >>= 1) {
            vs += __shfl_down(vs, o);
            vd += __shfl_down(vd, o);
        }
        if (lane == 0 && r < nrows) { es[base + r] = vs; ed[base + r] = vd; }
    }
    __syncthreads();
    unsigned* hbase = hb + (size_t)base * 32;
    for (int i = threadIdx.x; i < nrows * 32; i += 256) hbase[i] = hs[i];
}

// ---------------- aggregate: 2 nodes per wave (half-wave = one node, lane owns 2 features) ----
// Each hb dword = bf16 feature pair {2j, 2j+1}: 32 lanes cover a row with 2 accumulators.
// Half-waves are independent under shfl_xor offsets <=16. Output rows staged in LDS,
// flushed full-wave contiguous (sparse dword stores write-around L2 — R5 lesson).
// FUSE: next-layer gemm epilogue full-wave per row after a block barrier.
template<bool FUSE>
__global__ void gat_agg_fused(const unsigned* __restrict__ hb_in, const float* __restrict__ es_in,
                              const float* __restrict__ ed_in, const int* __restrict__ rowptr,
                              const int* __restrict__ csr_src, const float* __restrict__ bias,
                              const float* __restrict__ Wn, const float* __restrict__ ans,
                              const float* __restrict__ and_,
                              float* __restrict__ xout, unsigned* __restrict__ hb_out,
                              float* __restrict__ es_out, float* __restrict__ ed_out, int N) {
    extern __shared__ float smem[];
    constexpr int KP = 68;
    float* Ws = smem;                                        // [64][68] (FUSE only)
    float2* sw = (float2*)(smem + (FUSE ? 64 * KP : 0));     // [8][64] (src,w) pairs
    float* xs = (float*)((char*)sw + 8 * 64 * 8);            // [8][64] output rows
    unsigned* hpack = (unsigned*)((char*)xs + 8 * 64 * 4);   // [8][32] (FUSE only)

    int wave = threadIdx.x >> 6, lane = threadIdx.x & 63;
    int hw = lane >> 5, sub = lane & 31;
    int base8 = blockIdx.x * 8;
    int nl = 2 * wave + hw;                // node-local 0..7
    int node = base8 + nl;

    if (FUSE) {
        int c = threadIdx.x & 63;
        int q0 = threadIdx.x >> 6;
        #pragma unroll
        for (int it = 0; it < 4; ++it) {
            int q = q0 + 4 * it;
            float4 v;
            v.x = Wn[(4 * q + 0) * F + c];
            v.y = Wn[(4 * q + 1) * F + c];
            v.z = Wn[(4 * q + 2) * F + c];
            v.w = Wn[(4 * q + 3) * F + c];
            *(float4*)&Ws[c * KP + 4 * q] = v;
        }
    }

    if (node < N) {
        int beg = rowptr[node], end = rowptr[node + 1];
        int cnt = end - beg;
        float edn = ed_in[node];
        float accL, accH, den;
        if (cnt <= 64) {
            int s1 = 0, s2 = 0;
            float e1 = -1e30f, e2 = -1e30f;
            if (sub < cnt) {
                s1 = csr_src[beg + sub];
                float t = es_in[s1] + edn;
                e1 = t > 0.f ? t : 0.2f * t;
            }
            if (sub + 32 < cnt) {
                s2 = csr_src[beg + 32 + sub];
                float t = es_in[s2] + edn;
                e2 = t > 0.f ? t : 0.2f * t;
            }
            float m = fmaxf(e1, e2);
            #pragma unroll
            for (int o = 16; o > 0; o >>= 1) m = fmaxf(m, __shfl_xor(m, o));
            float w1 = (sub < cnt) ? __expf(e1 - m) : 0.f;
            float w2 = (sub + 32 < cnt) ? __expf(e2 - m) : 0.f;
            den = w1 + w2;
            #pragma unroll
            for (int o = 16; o > 0; o >>= 1) den += __shfl_xor(den, o);
            sw[nl * 64 + sub] = make_float2(__int_as_float(s1), w1);
            sw[nl * 64 + 32 + sub] = make_float2(__int_as_float(s2), w2);
            float l0 = 0.f, l1 = 0.f, l2 = 0.f, l3 = 0.f;
            float h0 = 0.f, h1 = 0.f, h2 = 0.f, h3 = 0.f;
            int i = 0;
            for (; i + 3 < cnt; i += 4) {
                float2 p0 = sw[nl * 64 + i];
                float2 p1 = sw[nl * 64 + i + 1];
                float2 p2 = sw[nl * 64 + i + 2];
                float2 p3 = sw[nl * 64 + i + 3];
                unsigned q0 = hb_in[(size_t)__float_as_int(p0.x) * 32 + sub];
                unsigned q1 = hb_in[(size_t)__float_as_int(p1.x) * 32 + sub];
                unsigned q2 = hb_in[(size_t)__float_as_int(p2.x) * 32 + sub];
                unsigned q3 = hb_in[(size_t)__float_as_int(p3.x) * 32 + sub];
                l0 = fmaf(p0.y, __uint_as_float(q0 << 16), l0);
                h0 = fmaf(p0.y, __uint_as_float(q0 & 0xFFFF0000u), h0);
                l1 = fmaf(p1.y, __uint_as_float(q1 << 16), l1);
                h1 = fmaf(p1.y, __uint_as_float(q1 & 0xFFFF0000u), h1);
                l2 = fmaf(p2.y, __uint_as_float(q2 << 16), l2);
                h2 = fmaf(p2.y, __uint_as_float(q2 & 0xFFFF0000u), h2);
                l3 = fmaf(p3.y, __uint_as_float(q3 << 16), l3);
                h3 = fmaf(p3.y, __uint_as_float(q3 & 0xFFFF0000u), h3);
            }
            for (; i < cnt; ++i) {
                float2 pp = sw[nl * 64 + i];
                unsigned q = hb_in[(size_t)__float_as_int(pp.x) * 32 + sub];
                l0 = fmaf(pp.y, __uint_as_float(q << 16), l0);
                h0 = fmaf(pp.y, __uint_as_float(q & 0xFFFF0000u), h0);
            }
            accL = (l0 + l1) + (l2 + l3);
            accH = (h0 + h1) + (h2 + h3);
        } else {
            // slow path (deg>64, ~1e-18 prob): half-wave strided max, serial accumulate
            float m = -1e30f;
            for (int j = beg + sub; j < end; j += 32) {
                float e = es_in[csr_src[j]] + edn;
                e = e > 0.f ? e : 0.2f * e;
                m = fmaxf(m, e);
            }
            #pragma unroll
            for (int o = 16; o > 0; o >>= 1) m = fmaxf(m, __shfl_xor(m, o));
            accL = 0.f; accH = 0.f; den = 0.f;
            for (int j = beg; j < end; ++j) {
                int s = csr_src[j];
                float e = es_in[s] + edn;
                e = e > 0.f ? e : 0.2f * e;
                float w = __expf(e - m);
                den += w;
                unsigned q = hb_in[(size_t)s * 32 + sub];
                accL = fmaf(w, __uint_as_float(q << 16), accL);
                accH = fmaf(w, __uint_as_float(q & 0xFFFF0000u), accH);
            }
        }
        float inv = 1.0f / (den + 1e-16f);
        float2 b2v = ((const float2*)bias)[sub];
        float vL = accL * inv + b2v.x;
        float vH = accH * inv + b2v.y;
        vL = vL > 0.f ? vL : 0.f;
        vH = vH > 0.f ? vH : 0.f;
        ((float2*)&xs[nl * 64])[sub] = make_float2(vL, vH);
    }
    __syncthreads();

    int nrows = min(8, N - base8);
    // coalesced xout flush
    {
        float* xbase = xout + (size_t)base8 * F;
        for (int i = threadIdx.x; i < nrows * 64; i += 256) xbase[i] = xs[i];
    }

    if (FUSE) {
        float as_l = ans[lane];
        float ad_l = and_[lane];
        #pragma unroll
        for (int rr = 0; rr < 2; ++rr) {
            int r = wave + 4 * rr;
            int nd = base8 + r;
            if (nd < N) {
                const float4* xv4 = (const float4*)&xs[r * 64];
                const float4* wv4 = (const float4*)&Ws[lane * KP];
                float a0 = 0.f, a1 = 0.f, a2 = 0.f, a3 = 0.f;
                #pragma unroll
                for (int k4 = 0; k4 < 16; ++k4) {
                    float4 xv = xv4[k4];
                    float4 wv = wv4[k4];
                    a0 = fmaf(xv.x, wv.x, a0);
                    a1 = fmaf(xv.y, wv.y, a1);
                    a2 = fmaf(xv.z, wv.z, a2);
                    a3 = fmaf(xv.w, wv.w, a3);
                }
                float hacc = (a0 + a1) + (a2 + a3);
                float vs = hacc * as_l;
                float vd = hacc * ad_l;
                #pragma unroll
                for (int o = 32; o > 0; o >>= 1) {
                    vs += __shfl_down(vs, o);
                    vd += __shfl_down(vd, o);
                }
                if (lane == 0) { es_out[nd] = vs; ed_out[nd] = vd; }
                unsigned ub = __float_as_uint(hacc);
                unsigned rb = (ub + 0x7FFF + ((ub >> 16) & 1)) >> 16;
                unsigned pb = (unsigned)__shfl_xor((int)rb, 1);
                if ((lane & 1) == 0) hpack[r * 32 + (lane >> 1)] = (pb << 16) | rb;
            }
        }
        __syncthreads();
        unsigned* hbase = hb_out + (size_t)base8 * 32;
        for (int i = threadIdx.x; i < nrows * 32; i += 256) hbase[i] = hpack[i];
    }
}

// ---------------- mean pooling ----------------
__global__ void pool_kernel(const float* __restrict__ x1, const float* __restrict__ x2,
                            const float* __restrict__ x3, const int* __restrict__ gstart,
                            float* __restrict__ pooled) {
    int g = blockIdx.x >> 2;
    int seg = blockIdx.x & 3;
    int f = threadIdx.x;
    int lane = f & 63;
    const float* src = (f < 64) ? x1 : (f < 128) ? x2 : x3;
    int lo = gstart[g], hi = gstart[g + 1];
    int len = hi - lo;
    int chunk = (len + 3) >> 2;
    int b = lo + seg * chunk;
    int e = min(hi, b + chunk);
    float s0 = 0.f, s1 = 0.f, s2 = 0.f, s3 = 0.f;
    int i = b;
    for (; i + 3 < e; i += 4) {
        s0 += src[(size_t)i * F + lane];
        s1 += src[(size_t)(i + 1) * F + lane];
        s2 += src[(size_t)(i + 2) * F + lane];
        s3 += src[(size_t)(i + 3) * F + lane];
    }
    for (; i < e; ++i) s0 += src[(size_t)i * F + lane];
    float s = (s0 + s1) + (s2 + s3);
    atomicAdd(&pooled[g * 192 + f], s);
}

// ---------------- final linear + softmax ----------------
__global__ void head_kernel(const float* __restrict__ pooled, const int* __restrict__ gstart,
                            const float* __restrict__ Wo, const float* __restrict__ bo,
                            float* __restrict__ out) {
    int g = blockIdx.x * blockDim.x + threadIdx.x;
    if (g >= GRAPHS) return;
    int cntg = gstart[g + 1] - gstart[g];
    float inv = 1.0f / fmaxf((float)cntg, 1.0f);
    float acc[CLASSES];
    #pragma unroll
    for (int c = 0; c < CLASSES; ++c) acc[c] = bo[c];
    for (int f = 0; f < 192; ++f) {
        float p = pooled[g * 192 + f] * inv;
        #pragma unroll
        for (int c = 0; c < CLASSES; ++c) acc[c] = fmaf(p, Wo[f * CLASSES + c], acc[c]);
    }
    float mx = acc[0];
    #pragma unroll
    for (int c = 1; c < CLASSES; ++c) mx = fmaxf(mx, acc[c]);
    float s = 0.f;
    #pragma unroll
    for (int c = 0; c < CLASSES; ++c) { acc[c] = __expf(acc[c] - mx); s += acc[c]; }
    float invs = 1.0f / s;
    #pragma unroll
    for (int c = 0; c < CLASSES; ++c) out[g * CLASSES + c] = acc[c] * invs;
}

extern "C" void kernel_launch(void* const* d_in, const int* in_sizes, int n_in,
                              void* d_out, int out_size, void* d_ws, size_t ws_size,
                              hipStream_t stream) {
    const float* x   = (const float*)d_in[0];
    const int* ei    = (const int*)d_in[1];
    const int* batch = (const int*)d_in[2];
    const float* W1  = (const float*)d_in[3];
    const float* a1s = (const float*)d_in[4];
    const float* a1d = (const float*)d_in[5];
    const float* b1  = (const float*)d_in[6];
    const float* W2  = (const float*)d_in[7];
    const float* a2s = (const float*)d_in[8];
    const float* a2d = (const float*)d_in[9];
    const float* b2  = (const float*)d_in[10];
    const float* W3  = (const float*)d_in[11];
    const float* a3s = (const float*)d_in[12];
    const float* a3d = (const float*)d_in[13];
    const float* b3  = (const float*)d_in[14];
    const float* Wo  = (const float*)d_in[15];
    const float* bo  = (const float*)d_in[16];
    float* out = (float*)d_out;

    const int N = in_sizes[2];
    const int E = in_sizes[1] / 2;
    const int TOT = E + N;
    const int NB = (N + 255) >> 8;
    const int M  = NB * NBLK;

    char* p = (char*)d_ws;
    auto alloc = [&](size_t bytes) { char* r = p; p += (bytes + 255) & ~(size_t)255; return r; };
    float* x1      = (float*)alloc((size_t)N * F * 4);
    float* x2      = (float*)alloc((size_t)N * F * 4);
    float* x3      = (float*)alloc((size_t)N * F * 4);
    unsigned* hbA  = (unsigned*)alloc((size_t)N * 32 * 4);
    unsigned* hbB  = (unsigned*)alloc((size_t)N * 32 * 4);
    float* esA     = (float*)alloc((size_t)N * 4);
    float* edA     = (float*)alloc((size_t)N * 4);
    float* esB     = (float*)alloc((size_t)N * 4);
    float* edB     = (float*)alloc((size_t)N * 4);
    int* rowptr    = (int*)alloc((size_t)(N + 1) * 4);
    int* csr_src   = (int*)alloc((size_t)TOT * 4);
    unsigned* stage= (unsigned*)alloc((size_t)E * 4);
    int* hist      = (int*)alloc((size_t)M * 4);
    int* shist     = (int*)alloc((size_t)M * 4);
    int* partial   = (int*)alloc((size_t)SCAN_T * 4);
    float* pooled  = (float*)alloc((size_t)GRAPHS * 192 * 4);
    int* gstart    = (int*)alloc((size_t)(GRAPHS + 1) * 4);

    hipMemsetAsync(pooled, 0, (size_t)GRAPHS * 192 * 4, stream);

    const int GB = (N + 15) / 16;
    const size_t SM128 = (size_t)(64 * 132 + 16 * 128) * 4 + 2048;
    const size_t SMF   = (size_t)(64 * 68) * 4 + 4096 + 2048 + 1024;   // Ws + sw + xs + hpack
    const size_t SMNF  = 4096 + 2048 + 1024;
    int agg_blocks = (N + 7) / 8;

    // CSR build
    hist_gb_kernel<<<NBLK + 3, 256, 0, stream>>>(ei, E, NB, hist, batch, N, gstart);
    hscan_partial<<<SCAN_T / 256, 256, 0, stream>>>(hist, M, partial);
    scan_block<<<1, SCAN_T, 0, stream>>>(partial);
    hscan_final<<<SCAN_T / 256, 256, 0, stream>>>(hist, partial, M, shist);
    scatter3<<<NBLK, 256, 0, stream>>>(ei, E, NB, shist, stage);
    place2<<<NB, 256, 0, stream>>>(stage, shist, rowptr, csr_src, N, E, NB);

    // layer 1 GEMM (K=128)
    gemm_kernel<128><<<GB, 256, SM128, stream>>>(x, W1, a1s, a1d, hbA, esA, edA, N);
    // agg1 + fused gemm2
    gat_agg_fused<true><<<agg_blocks, 256, SMF, stream>>>(hbA, esA, edA, rowptr, csr_src, b1,
                                                          W2, a2s, a2d, x1, hbB, esB, edB, N);
    // agg2 + fused gemm3
    gat_agg_fused<true><<<agg_blocks, 256, SMF, stream>>>(hbB, esB, edB, rowptr, csr_src, b2,
                                                          W3, a3s, a3d, x2, hbA, esA, edA, N);
    // agg3 (no fusion)
    gat_agg_fused<false><<<agg_blocks, 256, SMNF, stream>>>(hbA, esA, edA, rowptr, csr_src, b3,
                                                            nullptr, nullptr, nullptr,
                                                            x3, nullptr, nullptr, nullptr, N);

    // readout
    pool_kernel<<<GRAPHS * 4, 192, 0, stream>>>(x1, x2, x3, gstart, pooled);
    head_kernel<<<(GRAPHS + 255) / 256, 256, 0, stream>>>(pooled, gstart, Wo, bo, out);
}